// Round 2
// baseline (2028.892 us; speedup 1.0000x reference)
//
#include <hip/hip_runtime.h>
#include <cstdint>
#include <cmath>

#define B_ 2
#define C_ 64
#define H_ 128
#define W_ 240
#define HW_ (H_*W_)
#define DG_ 8
#define K_ 9
#define OFF_CH 144
#define MASK_CH 72
#define ALIGNED_SZ (B_*C_*HW_)   /* 3932160 floats */

// ---------------------------------------------------------------------------
// Kernel 1 v2: conv 3x3 (Cin=128=concat[nbr,ref], Cout=64) + LeakyReLU(0.1)
// Tile: 16 wide x 64 tall, 256 threads, 4 vertical pixels/thread, 8 oc/thread.
// grid (15, 2, B*8).  Weight LDS reads amortized 4x vs v1.
// ---------------------------------------------------------------------------
__global__ __launch_bounds__(256) void conv1_lrelu(
    const float* __restrict__ nbr, const float* __restrict__ ref,
    const float* __restrict__ w1, const float* __restrict__ b1,
    float* __restrict__ hbuf)
{
    const int bx = blockIdx.x, by = blockIdx.y;
    const int b   = blockIdx.z >> 3;
    const int ocs = (blockIdx.z & 7) << 3;
    const int tx  = threadIdx.x & 15, tyr = threadIdx.x >> 4;  // tyr 0..15
    const int x   = (bx << 4) + tx;
    const int y0  = (by << 6) + (tyr << 2);                    // 4 rows y0..y0+3

    __shared__ float s_in[8 * 1188];                 // 8 cin x 66 rows x 18 cols
    __shared__ __align__(16) float s_w[8 * 8 * 12];  // [cin][oc][12 pad]

    float acc[8][4];
#pragma unroll
    for (int oc = 0; oc < 8; ++oc) {
        float bv = b1[ocs + oc];
#pragma unroll
        for (int p = 0; p < 4; ++p) acc[oc][p] = bv;
    }

    for (int chunk = 0; chunk < 16; ++chunk) {
        const float* src = (chunk < 8)
            ? nbr + ((size_t)b * C_ + (chunk << 3)) * HW_
            : ref + ((size_t)b * C_ + ((chunk - 8) << 3)) * HW_;

        for (int idx = threadIdx.x; idx < 8 * 1188; idx += 256) {
            int c = idx / 1188, r = idx - c * 1188;
            int iy = r / 18, ix = r - iy * 18;
            int gy = (by << 6) + iy - 1, gx = (bx << 4) + ix - 1;
            float v = 0.f;
            if ((unsigned)gy < (unsigned)H_ && (unsigned)gx < (unsigned)W_)
                v = src[(size_t)c * HW_ + gy * W_ + gx];
            s_in[idx] = v;
        }
        for (int idx = threadIdx.x; idx < 8 * 8 * 9; idx += 256) {
            int c = idx / 72, r = idx - c * 72;
            int oc = r / 9, tap = r - oc * 9;
            s_w[(c * 8 + oc) * 12 + tap] =
                w1[(((size_t)(ocs + oc)) * 128 + (chunk << 3) + c) * 9 + tap];
        }
        __syncthreads();

#pragma unroll
        for (int c = 0; c < 8; ++c) {
            float v[6][3];
            const int base = c * 1188 + (tyr << 2) * 18 + tx;
#pragma unroll
            for (int r = 0; r < 6; ++r)
#pragma unroll
                for (int dx = 0; dx < 3; ++dx)
                    v[r][dx] = s_in[base + r * 18 + dx];
#pragma unroll
            for (int oc = 0; oc < 8; ++oc) {
                const float* wp = &s_w[(c * 8 + oc) * 12];
                float4 wa = *(const float4*)wp;
                float4 wb = *(const float4*)(wp + 4);
                float w8 = wp[8];
#pragma unroll
                for (int p = 0; p < 4; ++p) {
                    acc[oc][p] += v[p][0] * wa.x + v[p][1] * wa.y + v[p][2] * wa.z
                                + v[p + 1][0] * wa.w + v[p + 1][1] * wb.x + v[p + 1][2] * wb.y
                                + v[p + 2][0] * wb.z + v[p + 2][1] * wb.w + v[p + 2][2] * w8;
                }
            }
        }
        __syncthreads();
    }

#pragma unroll
    for (int oc = 0; oc < 8; ++oc)
#pragma unroll
        for (int p = 0; p < 4; ++p) {
            float v = acc[oc][p];
            v = (v >= 0.f) ? v : 0.1f * v;
            hbuf[(((size_t)b * C_ + ocs + oc) * H_ + y0 + p) * W_ + x] = v;
        }
}

// ---------------------------------------------------------------------------
// Kernel 2 v2: conv 3x3 (Cin=64, Cout=216); co<144 -> offset region of d_out,
// co>=144 -> sigmoid -> mask buffer.  Same 16x64 tile, 4 px/thread, 8 oc.
// grid (15, 2, B*27).
// ---------------------------------------------------------------------------
__global__ __launch_bounds__(256) void conv2_split(
    const float* __restrict__ hbuf,
    const float* __restrict__ w2, const float* __restrict__ b2,
    float* __restrict__ off_out, float* __restrict__ maskbuf)
{
    const int bx = blockIdx.x, by = blockIdx.y;
    const int b   = blockIdx.z / 27;
    const int ocs = (blockIdx.z % 27) << 3;
    const int tx  = threadIdx.x & 15, tyr = threadIdx.x >> 4;
    const int x   = (bx << 4) + tx;
    const int y0  = (by << 6) + (tyr << 2);

    __shared__ float s_in[8 * 1188];
    __shared__ __align__(16) float s_w[8 * 8 * 12];

    float acc[8][4];
#pragma unroll
    for (int oc = 0; oc < 8; ++oc) {
        float bv = b2[ocs + oc];
#pragma unroll
        for (int p = 0; p < 4; ++p) acc[oc][p] = bv;
    }

    for (int chunk = 0; chunk < 8; ++chunk) {
        const float* src = hbuf + ((size_t)b * C_ + (chunk << 3)) * HW_;

        for (int idx = threadIdx.x; idx < 8 * 1188; idx += 256) {
            int c = idx / 1188, r = idx - c * 1188;
            int iy = r / 18, ix = r - iy * 18;
            int gy = (by << 6) + iy - 1, gx = (bx << 4) + ix - 1;
            float v = 0.f;
            if ((unsigned)gy < (unsigned)H_ && (unsigned)gx < (unsigned)W_)
                v = src[(size_t)c * HW_ + gy * W_ + gx];
            s_in[idx] = v;
        }
        for (int idx = threadIdx.x; idx < 8 * 8 * 9; idx += 256) {
            int c = idx / 72, r = idx - c * 72;
            int oc = r / 9, tap = r - oc * 9;
            s_w[(c * 8 + oc) * 12 + tap] =
                w2[(((size_t)(ocs + oc)) * 64 + (chunk << 3) + c) * 9 + tap];
        }
        __syncthreads();

#pragma unroll
        for (int c = 0; c < 8; ++c) {
            float v[6][3];
            const int base = c * 1188 + (tyr << 2) * 18 + tx;
#pragma unroll
            for (int r = 0; r < 6; ++r)
#pragma unroll
                for (int dx = 0; dx < 3; ++dx)
                    v[r][dx] = s_in[base + r * 18 + dx];
#pragma unroll
            for (int oc = 0; oc < 8; ++oc) {
                const float* wp = &s_w[(c * 8 + oc) * 12];
                float4 wa = *(const float4*)wp;
                float4 wb = *(const float4*)(wp + 4);
                float w8 = wp[8];
#pragma unroll
                for (int p = 0; p < 4; ++p) {
                    acc[oc][p] += v[p][0] * wa.x + v[p][1] * wa.y + v[p][2] * wa.z
                                + v[p + 1][0] * wa.w + v[p + 1][1] * wb.x + v[p + 1][2] * wb.y
                                + v[p + 2][0] * wb.z + v[p + 2][1] * wb.w + v[p + 2][2] * w8;
                }
            }
        }
        __syncthreads();
    }

#pragma unroll
    for (int oc = 0; oc < 8; ++oc) {
        const int co = ocs + oc;
#pragma unroll
        for (int p = 0; p < 4; ++p) {
            float v = acc[oc][p];
            if (co < 144) {
                off_out[(((size_t)b * OFF_CH + co) * H_ + y0 + p) * W_ + x] = v;
            } else {
                maskbuf[(((size_t)b * MASK_CH + (co - 144)) * H_ + y0 + p) * W_ + x] =
                    1.f / (1.f + expf(-v));
            }
        }
    }
}

// ---------------------------------------------------------------------------
// Kernel 3: modulated deformable conv (unchanged from round 1).
// grid (15,8,B) block 256, one pixel/thread, 64 oc accumulated.
// ---------------------------------------------------------------------------
__global__ __launch_bounds__(256) void dconv_kernel(
    const float* __restrict__ xin,
    const float* __restrict__ offs,
    const float* __restrict__ maskbuf,
    const float* __restrict__ wd, const float* __restrict__ bd,
    float* __restrict__ outp)
{
    const int bx = blockIdx.x, by = blockIdx.y, b = blockIdx.z;
    const int tx = threadIdx.x & 15, ty = threadIdx.x >> 4;
    const int x = (bx << 4) + tx, y = (by << 4) + ty;
    const size_t pix = (size_t)y * W_ + x;

    __shared__ __align__(16) float s_w[16 * 9 * 64];   // 36 KB

    float acc[64];
#pragma unroll
    for (int i = 0; i < 64; ++i) acc[i] = bd[i];

    for (int chunk = 0; chunk < 4; ++chunk) {
        const int cin0 = chunk << 4;
        for (int idx = threadIdx.x; idx < 16 * 9 * 64; idx += 256) {
            int ci = idx / 576, r = idx - ci * 576;
            int k = r >> 6, oc = r & 63;
            s_w[idx] = wd[((size_t)oc * 64 + cin0 + ci) * 9 + k];
        }
        __syncthreads();

        for (int dgl = 0; dgl < 2; ++dgl) {
            const int dg = (chunk << 1) + dgl;
            const float* base = xin + ((size_t)b * C_ + dg * 8) * HW_;
            for (int k = 0; k < 9; ++k) {
                const int ky = k / 3 - 1, kx = k % 3 - 1;
                float dy = offs[((size_t)b * OFF_CH + dg * 18 + k) * HW_ + pix];
                float dx = offs[((size_t)b * OFF_CH + dg * 18 + 9 + k) * HW_ + pix];
                float m  = maskbuf[((size_t)b * MASK_CH + dg * 9 + k) * HW_ + pix];

                float py = (float)(y + ky) + dy;
                float px = (float)(x + kx) + dx;
                float y0f = floorf(py), x0f = floorf(px);
                float wy = py - y0f, wx = px - x0f;
                int y0 = (int)y0f, x0 = (int)x0f;

                const bool y0v = (unsigned)y0 < (unsigned)H_;
                const bool y1v = (unsigned)(y0 + 1) < (unsigned)H_;
                const bool x0v = (unsigned)x0 < (unsigned)W_;
                const bool x1v = (unsigned)(x0 + 1) < (unsigned)W_;

                float w00 = (1.f - wy) * (1.f - wx) * m; if (!(y0v && x0v)) w00 = 0.f;
                float w01 = (1.f - wy) * wx        * m; if (!(y0v && x1v)) w01 = 0.f;
                float w10 = wy        * (1.f - wx) * m; if (!(y1v && x0v)) w10 = 0.f;
                float w11 = wy        * wx         * m; if (!(y1v && x1v)) w11 = 0.f;

                int yc0 = min(max(y0, 0), H_ - 1), yc1 = min(max(y0 + 1, 0), H_ - 1);
                int xc0 = min(max(x0, 0), W_ - 1), xc1 = min(max(x0 + 1, 0), W_ - 1);
                const int p00 = yc0 * W_ + xc0, p01 = yc0 * W_ + xc1;
                const int p10 = yc1 * W_ + xc0, p11 = yc1 * W_ + xc1;

                for (int cl = 0; cl < 8; ++cl) {
                    const int ci = (dgl << 3) + cl;
                    const float* cb = base + (size_t)cl * HW_;
                    float s = cb[p00] * w00 + cb[p01] * w01
                            + cb[p10] * w10 + cb[p11] * w11;
                    const float* wp = &s_w[(ci * 9 + k) * 64];
#pragma unroll
                    for (int oc = 0; oc < 64; oc += 4) {
                        float4 w4 = *(const float4*)(wp + oc);
                        acc[oc]     += s * w4.x;
                        acc[oc + 1] += s * w4.y;
                        acc[oc + 2] += s * w4.z;
                        acc[oc + 3] += s * w4.w;
                    }
                }
            }
        }
        __syncthreads();
    }

#pragma unroll
    for (int oc = 0; oc < 64; ++oc)
        outp[(((size_t)b * C_ + oc) * H_ + y) * W_ + x] = acc[oc];
}

// ---------------------------------------------------------------------------
extern "C" void kernel_launch(void* const* d_in, const int* in_sizes, int n_in,
                              void* d_out, int out_size, void* d_ws, size_t ws_size,
                              hipStream_t stream)
{
    const float* nbr = (const float*)d_in[0];
    const float* ref = (const float*)d_in[1];
    const float* w1  = (const float*)d_in[2];
    const float* b1  = (const float*)d_in[3];
    const float* w2  = (const float*)d_in[4];
    const float* b2  = (const float*)d_in[5];
    const float* wd  = (const float*)d_in[6];
    const float* bd  = (const float*)d_in[7];

    float* out     = (float*)d_out;
    float* off_out = out + ALIGNED_SZ;

    float* ws      = (float*)d_ws;
    float* hbuf    = ws;                        // B*C*H*W   = 3,932,160 f32
    float* maskbuf = ws + (size_t)ALIGNED_SZ;   // B*72*H*W  = 4,423,680 f32

    dim3 blk(256, 1, 1);
    conv1_lrelu<<<dim3(15, 2, B_ * 8),  blk, 0, stream>>>(nbr, ref, w1, b1, hbuf);
    conv2_split<<<dim3(15, 2, B_ * 27), blk, 0, stream>>>(hbuf, w2, b2, off_out, maskbuf);
    dconv_kernel<<<dim3(15, 8, B_),     blk, 0, stream>>>(nbr, off_out, maskbuf, wd, bd, out);
}

// Round 3
// 441.715 us; speedup vs baseline: 4.5932x; 4.5932x over previous
//
#include <hip/hip_runtime.h>
#include <cstdint>
#include <cmath>

#define B_ 2
#define C_ 64
#define H_ 128
#define W_ 240
#define HW_ (H_*W_)
#define OFF_CH 144
#define MASK_CH 72
#define ALIGNED_SZ (B_*C_*HW_)   /* 3932160 floats */

typedef __bf16 bf16x8 __attribute__((ext_vector_type(8)));
typedef float f32x4 __attribute__((ext_vector_type(4)));
typedef short short4v __attribute__((ext_vector_type(4)));
typedef unsigned short ushort_t;

__device__ __forceinline__ ushort_t f2bf(float f) {
    unsigned u = __float_as_uint(f);
    u += 0x7fffu + ((u >> 16) & 1u);          // round-to-nearest-even
    return (ushort_t)(u >> 16);
}
__device__ __forceinline__ float bf2f(ushort_t b) {
    return __uint_as_float((unsigned)b << 16);
}

// workspace layout (byte offsets); total 32,845,824 B  (< 33.4 MB proven available)
#define W1P_OFF  0u           /* [9][64][128]  bf16 = 147,456 B  */
#define W2P_OFF  147456u      /* [9][224][64]  bf16 = 258,048 B  */
#define PIN_OFF  405504u      /* [B][H][W][128] bf16 = 15,728,640 */
#define HBUF_OFF 16134144u    /* [B][H][W][64]  bf16 =  7,864,320 */
#define MASK_OFF 23998464u    /* [B][72][H][W]  bf16 =  8,847,360 */

// ---------------------------------------------------------------------------
// Repack weights: w1 [64][128][9] f32 -> w1p [tap][oc][ci] bf16
//                 w2 [216][64][9] f32 -> w2p [tap][224(pad0)][ci] bf16
// ---------------------------------------------------------------------------
__global__ __launch_bounds__(256) void pack_weights(
    const float* __restrict__ w1, const float* __restrict__ w2,
    ushort_t* __restrict__ w1p, ushort_t* __restrict__ w2p)
{
    int t = blockIdx.x * 256 + threadIdx.x;
    if (t < 73728) {
        int ci = t & 127, r = t >> 7;          // r = tap*64 + oc
        int oc = r & 63, tap = r >> 6;
        w1p[t] = f2bf(w1[((size_t)oc * 128 + ci) * 9 + tap]);
    } else if (t < 73728 + 129024) {
        int f = t - 73728;                     // f = (tap*224 + oc)*64 + ci
        int ci = f & 63, r = f >> 6;
        int oc = r % 224, tap = r / 224;
        float v = (oc < 216) ? w2[((size_t)oc * 64 + ci) * 9 + tap] : 0.f;
        w2p[f] = f2bf(v);
    }
}

// ---------------------------------------------------------------------------
// Repack input: nbr/ref [b][64][HW] f32 -> pin [b*HW + pix][128] bf16
// (channels-last; ci 0..63 = nbr, 64..127 = ref)
// ---------------------------------------------------------------------------
__global__ __launch_bounds__(256) void pack_input(
    const float* __restrict__ nbr, const float* __restrict__ ref,
    ushort_t* __restrict__ pin)
{
    int f = blockIdx.x * 256 + threadIdx.x;    // < 983040 = B*HW*16
    int civec = f & 15;
    int rem = f >> 4;                          // b*HW + pix
    int b = rem / HW_, pix = rem - b * HW_;
    const float* src = (civec < 8) ? (nbr + (size_t)b * 64 * HW_)
                                   : (ref + (size_t)b * 64 * HW_);
    int cbase = (civec & 7) * 8;
    union { ushort_t u[8]; int4 v; } o;
#pragma unroll
    for (int j = 0; j < 8; ++j)
        o.u[j] = f2bf(src[(size_t)(cbase + j) * HW_ + pix]);
    *(int4*)&pin[(size_t)rem * 128 + civec * 8] = o.v;
}

// ---------------------------------------------------------------------------
// conv1 via MFMA implicit GEMM (per-tap).  Block: 64 oc x 48 px (1 row strip),
// 4 waves, each wave 16 oc x 48 px (3 accumulators). K chunked by 32 ci.
// LDS: s_in [3 rows][50 cols][ci 32 pad40], s_w [9 taps][64 oc][ci pad40].
// Writes hbuf channels-last bf16 with bias+LeakyReLU.
// grid (5, 128, 2)
// ---------------------------------------------------------------------------
__global__ __launch_bounds__(256) void conv1_mfma(
    const ushort_t* __restrict__ pin, const float* __restrict__ b1,
    const ushort_t* __restrict__ w1p, ushort_t* __restrict__ hbuf)
{
    const int bx = blockIdx.x, y = blockIdx.y, b = blockIdx.z;
    const int x0 = bx * 48;
    const int tid = threadIdx.x;
    const int wv = tid >> 6, lane = tid & 63;
    const int l15 = lane & 15, k8 = (lane >> 4) << 3;

    __shared__ __align__(16) ushort_t s_in[3 * 50 * 40];  // 12,000 B
    __shared__ __align__(16) ushort_t s_w[9 * 64 * 40];   // 46,080 B

    f32x4 acc[3];
#pragma unroll
    for (int i = 0; i < 3; ++i) acc[i] = (f32x4){0.f, 0.f, 0.f, 0.f};

    for (int chunk = 0; chunk < 4; ++chunk) {
        const int ci0 = chunk << 5;
        for (int i = tid; i < 600; i += 256) {            // input tile
            int cvec = i & 3, rc = i >> 2;
            int row = rc / 50, col = rc - row * 50;
            int gy = y + row - 1, gx = x0 + col - 1;
            int4 v = {0, 0, 0, 0};
            if ((unsigned)gy < (unsigned)H_ && (unsigned)gx < (unsigned)W_)
                v = *(const int4*)&pin[(((size_t)b * H_ + gy) * W_ + gx) * 128 + ci0 + cvec * 8];
            *(int4*)&s_in[(row * 50 + col) * 40 + cvec * 8] = v;
        }
        for (int i = tid; i < 2304; i += 256) {           // weights
            int cvec = i & 3, to = i >> 2;                // to = tap*64+oc
            int4 v = *(const int4*)&w1p[(size_t)to * 128 + ci0 + cvec * 8];
            *(int4*)&s_w[to * 40 + cvec * 8] = v;
        }
        __syncthreads();

#pragma unroll
        for (int tap = 0; tap < 9; ++tap) {
            const int ky = tap / 3, kx = tap - ky * 3;
            bf16x8 a = *(const bf16x8*)&s_w[((tap * 64) + (wv << 4) + l15) * 40 + k8];
#pragma unroll
            for (int pt = 0; pt < 3; ++pt) {
                int col = (pt << 4) + l15 + kx;
                bf16x8 bb = *(const bf16x8*)&s_in[(ky * 50 + col) * 40 + k8];
                acc[pt] = __builtin_amdgcn_mfma_f32_16x16x32_bf16(a, bb, acc[pt], 0, 0, 0);
            }
        }
        __syncthreads();
    }

    const int ocb = (wv << 4) + ((lane >> 4) << 2);       // D row = (lane>>4)*4+reg
    float bias[4];
#pragma unroll
    for (int r = 0; r < 4; ++r) bias[r] = b1[ocb + r];
#pragma unroll
    for (int pt = 0; pt < 3; ++pt) {
        int gx = x0 + (pt << 4) + l15;                    // D col = lane&15
        union { ushort_t u[4]; short4v s; } o;
#pragma unroll
        for (int r = 0; r < 4; ++r) {
            float v = acc[pt][r] + bias[r];
            v = (v >= 0.f) ? v : 0.1f * v;
            o.u[r] = f2bf(v);
        }
        *(short4v*)&hbuf[(((size_t)b * H_ + y) * W_ + gx) * 64 + ocb] = o.s;
    }
}

// ---------------------------------------------------------------------------
// conv2 via MFMA implicit GEMM.  Cout padded 216->224, 4 groups of 64 oc.
// Same structure as conv1 (Cin=64 -> 2 chunks).  Outputs: co<144 -> f32
// offsets in d_out; 144<=co<216 -> sigmoid -> bf16 mask buffer.
// grid (5, 128, 8)   (z = b*4 + ocg)
// ---------------------------------------------------------------------------
__global__ __launch_bounds__(256) void conv2_mfma(
    const ushort_t* __restrict__ hbuf, const float* __restrict__ b2,
    const ushort_t* __restrict__ w2p,
    float* __restrict__ off_out, ushort_t* __restrict__ maskbuf)
{
    const int bx = blockIdx.x, y = blockIdx.y;
    const int b = blockIdx.z >> 2, ocg = blockIdx.z & 3;
    const int x0 = bx * 48;
    const int tid = threadIdx.x;
    const int wv = tid >> 6, lane = tid & 63;
    const int l15 = lane & 15, k8 = (lane >> 4) << 3;

    __shared__ __align__(16) ushort_t s_in[3 * 50 * 40];
    __shared__ __align__(16) ushort_t s_w[9 * 64 * 40];

    f32x4 acc[3];
#pragma unroll
    for (int i = 0; i < 3; ++i) acc[i] = (f32x4){0.f, 0.f, 0.f, 0.f};

    for (int chunk = 0; chunk < 2; ++chunk) {
        const int ci0 = chunk << 5;
        for (int i = tid; i < 600; i += 256) {
            int cvec = i & 3, rc = i >> 2;
            int row = rc / 50, col = rc - row * 50;
            int gy = y + row - 1, gx = x0 + col - 1;
            int4 v = {0, 0, 0, 0};
            if ((unsigned)gy < (unsigned)H_ && (unsigned)gx < (unsigned)W_)
                v = *(const int4*)&hbuf[(((size_t)b * H_ + gy) * W_ + gx) * 64 + ci0 + cvec * 8];
            *(int4*)&s_in[(row * 50 + col) * 40 + cvec * 8] = v;
        }
        for (int i = tid; i < 2304; i += 256) {
            int cvec = i & 3, to = i >> 2;                // to = tap*64+oc_l
            int tap = to >> 6, oc_l = to & 63;
            int4 v = *(const int4*)&w2p[((size_t)tap * 224 + (ocg << 6) + oc_l) * 64 + ci0 + cvec * 8];
            *(int4*)&s_w[to * 40 + cvec * 8] = v;
        }
        __syncthreads();

#pragma unroll
        for (int tap = 0; tap < 9; ++tap) {
            const int ky = tap / 3, kx = tap - ky * 3;
            bf16x8 a = *(const bf16x8*)&s_w[((tap * 64) + (wv << 4) + l15) * 40 + k8];
#pragma unroll
            for (int pt = 0; pt < 3; ++pt) {
                int col = (pt << 4) + l15 + kx;
                bf16x8 bb = *(const bf16x8*)&s_in[(ky * 50 + col) * 40 + k8];
                acc[pt] = __builtin_amdgcn_mfma_f32_16x16x32_bf16(a, bb, acc[pt], 0, 0, 0);
            }
        }
        __syncthreads();
    }

    const int ocb = (wv << 4) + ((lane >> 4) << 2);
#pragma unroll
    for (int pt = 0; pt < 3; ++pt) {
        int gx = x0 + (pt << 4) + l15;
#pragma unroll
        for (int r = 0; r < 4; ++r) {
            int co = (ocg << 6) + ocb + r;
            if (co < 216) {
                float v = acc[pt][r] + b2[co];
                if (co < 144) {
                    off_out[((size_t)b * OFF_CH + co) * HW_ + y * W_ + gx] = v;
                } else {
                    maskbuf[((size_t)b * MASK_CH + (co - 144)) * HW_ + y * W_ + gx] =
                        f2bf(1.f / (1.f + expf(-v)));
                }
            }
        }
    }
}

// ---------------------------------------------------------------------------
// Kernel 3: modulated deformable conv (round-1 proven version; mask now bf16).
// grid (15,8,B) block 256, one pixel/thread, 64 oc accumulated.
// ---------------------------------------------------------------------------
__global__ __launch_bounds__(256) void dconv_kernel(
    const float* __restrict__ xin,
    const float* __restrict__ offs,
    const ushort_t* __restrict__ maskbuf,
    const float* __restrict__ wd, const float* __restrict__ bd,
    float* __restrict__ outp)
{
    const int bx = blockIdx.x, by = blockIdx.y, b = blockIdx.z;
    const int tx = threadIdx.x & 15, ty = threadIdx.x >> 4;
    const int x = (bx << 4) + tx, y = (by << 4) + ty;
    const size_t pix = (size_t)y * W_ + x;

    __shared__ __align__(16) float s_w[16 * 9 * 64];   // 36 KB

    float acc[64];
#pragma unroll
    for (int i = 0; i < 64; ++i) acc[i] = bd[i];

    for (int chunk = 0; chunk < 4; ++chunk) {
        const int cin0 = chunk << 4;
        for (int idx = threadIdx.x; idx < 16 * 9 * 64; idx += 256) {
            int ci = idx / 576, r = idx - ci * 576;
            int k = r >> 6, oc = r & 63;
            s_w[idx] = wd[((size_t)oc * 64 + cin0 + ci) * 9 + k];
        }
        __syncthreads();

        for (int dgl = 0; dgl < 2; ++dgl) {
            const int dg = (chunk << 1) + dgl;
            const float* base = xin + ((size_t)b * C_ + dg * 8) * HW_;
            for (int k = 0; k < 9; ++k) {
                const int ky = k / 3 - 1, kx = k % 3 - 1;
                float dy = offs[((size_t)b * OFF_CH + dg * 18 + k) * HW_ + pix];
                float dx = offs[((size_t)b * OFF_CH + dg * 18 + 9 + k) * HW_ + pix];
                float m  = bf2f(maskbuf[((size_t)b * MASK_CH + dg * 9 + k) * HW_ + pix]);

                float py = (float)(y + ky) + dy;
                float px = (float)(x + kx) + dx;
                float y0f = floorf(py), x0f = floorf(px);
                float wy = py - y0f, wx = px - x0f;
                int y0 = (int)y0f, x0 = (int)x0f;

                const bool y0v = (unsigned)y0 < (unsigned)H_;
                const bool y1v = (unsigned)(y0 + 1) < (unsigned)H_;
                const bool x0v = (unsigned)x0 < (unsigned)W_;
                const bool x1v = (unsigned)(x0 + 1) < (unsigned)W_;

                float w00 = (1.f - wy) * (1.f - wx) * m; if (!(y0v && x0v)) w00 = 0.f;
                float w01 = (1.f - wy) * wx        * m; if (!(y0v && x1v)) w01 = 0.f;
                float w10 = wy        * (1.f - wx) * m; if (!(y1v && x0v)) w10 = 0.f;
                float w11 = wy        * wx         * m; if (!(y1v && x1v)) w11 = 0.f;

                int yc0 = min(max(y0, 0), H_ - 1), yc1 = min(max(y0 + 1, 0), H_ - 1);
                int xc0 = min(max(x0, 0), W_ - 1), xc1 = min(max(x0 + 1, 0), W_ - 1);
                const int p00 = yc0 * W_ + xc0, p01 = yc0 * W_ + xc1;
                const int p10 = yc1 * W_ + xc0, p11 = yc1 * W_ + xc1;

                for (int cl = 0; cl < 8; ++cl) {
                    const int ci = (dgl << 3) + cl;
                    const float* cb = base + (size_t)cl * HW_;
                    float s = cb[p00] * w00 + cb[p01] * w01
                            + cb[p10] * w10 + cb[p11] * w11;
                    const float* wp = &s_w[(ci * 9 + k) * 64];
#pragma unroll
                    for (int oc = 0; oc < 64; oc += 4) {
                        float4 w4 = *(const float4*)(wp + oc);
                        acc[oc]     += s * w4.x;
                        acc[oc + 1] += s * w4.y;
                        acc[oc + 2] += s * w4.z;
                        acc[oc + 3] += s * w4.w;
                    }
                }
            }
        }
        __syncthreads();
    }

#pragma unroll
    for (int oc = 0; oc < 64; ++oc)
        outp[(((size_t)b * C_ + oc) * H_ + y) * W_ + x] = acc[oc];
}

// ---------------------------------------------------------------------------
extern "C" void kernel_launch(void* const* d_in, const int* in_sizes, int n_in,
                              void* d_out, int out_size, void* d_ws, size_t ws_size,
                              hipStream_t stream)
{
    const float* nbr = (const float*)d_in[0];
    const float* ref = (const float*)d_in[1];
    const float* w1  = (const float*)d_in[2];
    const float* b1  = (const float*)d_in[3];
    const float* w2  = (const float*)d_in[4];
    const float* b2  = (const float*)d_in[5];
    const float* wd  = (const float*)d_in[6];
    const float* bd  = (const float*)d_in[7];

    float* out     = (float*)d_out;
    float* off_out = out + ALIGNED_SZ;

    char* ws = (char*)d_ws;
    ushort_t* w1p   = (ushort_t*)(ws + W1P_OFF);
    ushort_t* w2p   = (ushort_t*)(ws + W2P_OFF);
    ushort_t* pin   = (ushort_t*)(ws + PIN_OFF);
    ushort_t* hbufp = (ushort_t*)(ws + HBUF_OFF);
    ushort_t* maskp = (ushort_t*)(ws + MASK_OFF);

    dim3 blk(256, 1, 1);
    pack_weights<<<792, blk, 0, stream>>>(w1, w2, w1p, w2p);
    pack_input<<<3840, blk, 0, stream>>>(nbr, ref, pin);
    conv1_mfma<<<dim3(5, 128, 2), blk, 0, stream>>>(pin, b1, w1p, hbufp);
    conv2_mfma<<<dim3(5, 128, 8), blk, 0, stream>>>(hbufp, b2, w2p, off_out, maskp);
    dconv_kernel<<<dim3(15, 8, 2), blk, 0, stream>>>(nbr, off_out, maskp, wd, bd, out);
}

// Round 4
// 273.377 us; speedup vs baseline: 7.4216x; 1.6158x over previous
//
#include <hip/hip_runtime.h>
#include <cstdint>
#include <cmath>

#define B_ 2
#define C_ 64
#define H_ 128
#define W_ 240
#define HW_ (H_*W_)
#define OFF_CH 144
#define MASK_CH 72
#define ALIGNED_SZ (B_*C_*HW_)   /* 3932160 floats */

typedef __bf16 bf16x8 __attribute__((ext_vector_type(8)));
typedef float f32x4 __attribute__((ext_vector_type(4)));
typedef short short4v __attribute__((ext_vector_type(4)));
typedef unsigned short ushort_t;

__device__ __forceinline__ ushort_t f2bf(float f) {
    unsigned u = __float_as_uint(f);
    u += 0x7fffu + ((u >> 16) & 1u);          // round-to-nearest-even
    return (ushort_t)(u >> 16);
}
__device__ __forceinline__ float bf2f(ushort_t b) {
    return __uint_as_float((unsigned)b << 16);
}
__device__ __forceinline__ float bf_lo(int q) {   // low bf16 of packed pair
    return __uint_as_float((unsigned)q << 16);
}
__device__ __forceinline__ float bf_hi(int q) {   // high bf16 of packed pair
    return __uint_as_float((unsigned)q & 0xffff0000u);
}

// workspace layout (byte offsets); total 32,919,552 B (< 33.4 MB proven OK)
#define W1P_OFF  0u           /* [9][64][128]  bf16 = 147,456 B  */
#define W2P_OFF  147456u      /* [9][224][64]  bf16 = 258,048 B  */
#define PIN_OFF  405504u      /* [B][H][W][128] bf16 = 15,728,640 */
#define HBUF_OFF 16134144u    /* [B][H][W][64]  bf16 =  7,864,320 */
#define MASK_OFF 23998464u    /* [B][72][H][W]  bf16 =  8,847,360 */
#define WDP_OFF  32845824u    /* [18][4][64][8] bf16 =     73,728 */

// ---------------------------------------------------------------------------
// Repack weights: w1 -> w1p [tap][oc][ci];  w2 -> w2p [tap][224][ci];
// wd -> wdp exact A-fragment layout for dconv: [slice(18)][wave(4)][lane][8]
//   oc = wave*16 + (lane&15);  K = slice*32 + (lane>>4)*8 + j;
//   K -> dg=K/72, tap=(K%72)/8, ci=dg*8+(K%8)
// ---------------------------------------------------------------------------
__global__ __launch_bounds__(256) void pack_weights(
    const float* __restrict__ w1, const float* __restrict__ w2,
    const float* __restrict__ wd,
    ushort_t* __restrict__ w1p, ushort_t* __restrict__ w2p,
    ushort_t* __restrict__ wdp)
{
    int t = blockIdx.x * 256 + threadIdx.x;
    if (t < 73728) {
        int ci = t & 127, r = t >> 7;          // r = tap*64 + oc
        int oc = r & 63, tap = r >> 6;
        w1p[t] = f2bf(w1[((size_t)oc * 128 + ci) * 9 + tap]);
    } else if (t < 73728 + 129024) {
        int f = t - 73728;                     // f = (tap*224 + oc)*64 + ci
        int ci = f & 63, r = f >> 6;
        int oc = r % 224, tap = r / 224;
        float v = (oc < 216) ? w2[((size_t)oc * 64 + ci) * 9 + tap] : 0.f;
        w2p[f] = f2bf(v);
    } else if (t < 73728 + 129024 + 36864) {
        int f = t - 202752;
        int j = f & 7, lane = (f >> 3) & 63, sg = f >> 9;  // sg = s*4+g
        int g = sg & 3, s = sg >> 2;
        int oc = g * 16 + (lane & 15);
        int K = s * 32 + ((lane >> 4) << 3) + j;
        int dg = K / 72, rr = K - dg * 72;
        int tap = rr >> 3, ci = (dg << 3) + (rr & 7);
        wdp[f] = f2bf(wd[((size_t)oc * 64 + ci) * 9 + tap]);
    }
}

// ---------------------------------------------------------------------------
// Repack input: nbr/ref [b][64][HW] f32 -> pin [b*HW + pix][128] bf16
// (channels-last; ci 0..63 = nbr, 64..127 = ref)
// ---------------------------------------------------------------------------
__global__ __launch_bounds__(256) void pack_input(
    const float* __restrict__ nbr, const float* __restrict__ ref,
    ushort_t* __restrict__ pin)
{
    int f = blockIdx.x * 256 + threadIdx.x;    // < 983040 = B*HW*16
    int civec = f & 15;
    int rem = f >> 4;                          // b*HW + pix
    int b = rem / HW_, pix = rem - b * HW_;
    const float* src = (civec < 8) ? (nbr + (size_t)b * 64 * HW_)
                                   : (ref + (size_t)b * 64 * HW_);
    int cbase = (civec & 7) * 8;
    union { ushort_t u[8]; int4 v; } o;
#pragma unroll
    for (int j = 0; j < 8; ++j)
        o.u[j] = f2bf(src[(size_t)(cbase + j) * HW_ + pix]);
    *(int4*)&pin[(size_t)rem * 128 + civec * 8] = o.v;
}

// ---------------------------------------------------------------------------
// conv1 via MFMA implicit GEMM (unchanged, proven).
// ---------------------------------------------------------------------------
__global__ __launch_bounds__(256) void conv1_mfma(
    const ushort_t* __restrict__ pin, const float* __restrict__ b1,
    const ushort_t* __restrict__ w1p, ushort_t* __restrict__ hbuf)
{
    const int bx = blockIdx.x, y = blockIdx.y, b = blockIdx.z;
    const int x0 = bx * 48;
    const int tid = threadIdx.x;
    const int wv = tid >> 6, lane = tid & 63;
    const int l15 = lane & 15, k8 = (lane >> 4) << 3;

    __shared__ __align__(16) ushort_t s_in[3 * 50 * 40];
    __shared__ __align__(16) ushort_t s_w[9 * 64 * 40];

    f32x4 acc[3];
#pragma unroll
    for (int i = 0; i < 3; ++i) acc[i] = (f32x4){0.f, 0.f, 0.f, 0.f};

    for (int chunk = 0; chunk < 4; ++chunk) {
        const int ci0 = chunk << 5;
        for (int i = tid; i < 600; i += 256) {
            int cvec = i & 3, rc = i >> 2;
            int row = rc / 50, col = rc - row * 50;
            int gy = y + row - 1, gx = x0 + col - 1;
            int4 v = {0, 0, 0, 0};
            if ((unsigned)gy < (unsigned)H_ && (unsigned)gx < (unsigned)W_)
                v = *(const int4*)&pin[(((size_t)b * H_ + gy) * W_ + gx) * 128 + ci0 + cvec * 8];
            *(int4*)&s_in[(row * 50 + col) * 40 + cvec * 8] = v;
        }
        for (int i = tid; i < 2304; i += 256) {
            int cvec = i & 3, to = i >> 2;
            int4 v = *(const int4*)&w1p[(size_t)to * 128 + ci0 + cvec * 8];
            *(int4*)&s_w[to * 40 + cvec * 8] = v;
        }
        __syncthreads();

#pragma unroll
        for (int tap = 0; tap < 9; ++tap) {
            const int ky = tap / 3, kx = tap - ky * 3;
            bf16x8 a = *(const bf16x8*)&s_w[((tap * 64) + (wv << 4) + l15) * 40 + k8];
#pragma unroll
            for (int pt = 0; pt < 3; ++pt) {
                int col = (pt << 4) + l15 + kx;
                bf16x8 bb = *(const bf16x8*)&s_in[(ky * 50 + col) * 40 + k8];
                acc[pt] = __builtin_amdgcn_mfma_f32_16x16x32_bf16(a, bb, acc[pt], 0, 0, 0);
            }
        }
        __syncthreads();
    }

    const int ocb = (wv << 4) + ((lane >> 4) << 2);
    float bias[4];
#pragma unroll
    for (int r = 0; r < 4; ++r) bias[r] = b1[ocb + r];
#pragma unroll
    for (int pt = 0; pt < 3; ++pt) {
        int gx = x0 + (pt << 4) + l15;
        union { ushort_t u[4]; short4v s; } o;
#pragma unroll
        for (int r = 0; r < 4; ++r) {
            float v = acc[pt][r] + bias[r];
            v = (v >= 0.f) ? v : 0.1f * v;
            o.u[r] = f2bf(v);
        }
        *(short4v*)&hbuf[(((size_t)b * H_ + y) * W_ + gx) * 64 + ocb] = o.s;
    }
}

// ---------------------------------------------------------------------------
// conv2 via MFMA implicit GEMM (unchanged, proven).
// ---------------------------------------------------------------------------
__global__ __launch_bounds__(256) void conv2_mfma(
    const ushort_t* __restrict__ hbuf, const float* __restrict__ b2,
    const ushort_t* __restrict__ w2p,
    float* __restrict__ off_out, ushort_t* __restrict__ maskbuf)
{
    const int bx = blockIdx.x, y = blockIdx.y;
    const int b = blockIdx.z >> 2, ocg = blockIdx.z & 3;
    const int x0 = bx * 48;
    const int tid = threadIdx.x;
    const int wv = tid >> 6, lane = tid & 63;
    const int l15 = lane & 15, k8 = (lane >> 4) << 3;

    __shared__ __align__(16) ushort_t s_in[3 * 50 * 40];
    __shared__ __align__(16) ushort_t s_w[9 * 64 * 40];

    f32x4 acc[3];
#pragma unroll
    for (int i = 0; i < 3; ++i) acc[i] = (f32x4){0.f, 0.f, 0.f, 0.f};

    for (int chunk = 0; chunk < 2; ++chunk) {
        const int ci0 = chunk << 5;
        for (int i = tid; i < 600; i += 256) {
            int cvec = i & 3, rc = i >> 2;
            int row = rc / 50, col = rc - row * 50;
            int gy = y + row - 1, gx = x0 + col - 1;
            int4 v = {0, 0, 0, 0};
            if ((unsigned)gy < (unsigned)H_ && (unsigned)gx < (unsigned)W_)
                v = *(const int4*)&hbuf[(((size_t)b * H_ + gy) * W_ + gx) * 64 + ci0 + cvec * 8];
            *(int4*)&s_in[(row * 50 + col) * 40 + cvec * 8] = v;
        }
        for (int i = tid; i < 2304; i += 256) {
            int cvec = i & 3, to = i >> 2;
            int tap = to >> 6, oc_l = to & 63;
            int4 v = *(const int4*)&w2p[((size_t)tap * 224 + (ocg << 6) + oc_l) * 64 + ci0 + cvec * 8];
            *(int4*)&s_w[to * 40 + cvec * 8] = v;
        }
        __syncthreads();

#pragma unroll
        for (int tap = 0; tap < 9; ++tap) {
            const int ky = tap / 3, kx = tap - ky * 3;
            bf16x8 a = *(const bf16x8*)&s_w[((tap * 64) + (wv << 4) + l15) * 40 + k8];
#pragma unroll
            for (int pt = 0; pt < 3; ++pt) {
                int col = (pt << 4) + l15 + kx;
                bf16x8 bb = *(const bf16x8*)&s_in[(ky * 50 + col) * 40 + k8];
                acc[pt] = __builtin_amdgcn_mfma_f32_16x16x32_bf16(a, bb, acc[pt], 0, 0, 0);
            }
        }
        __syncthreads();
    }

    const int ocb = (wv << 4) + ((lane >> 4) << 2);
#pragma unroll
    for (int pt = 0; pt < 3; ++pt) {
        int gx = x0 + (pt << 4) + l15;
#pragma unroll
        for (int r = 0; r < 4; ++r) {
            int co = (ocg << 6) + ocb + r;
            if (co < 216) {
                float v = acc[pt][r] + b2[co];
                if (co < 144) {
                    off_out[((size_t)b * OFF_CH + co) * HW_ + y * W_ + gx] = v;
                } else {
                    maskbuf[((size_t)b * MASK_CH + (co - 144)) * HW_ + y * W_ + gx] =
                        f2bf(1.f / (1.f + expf(-v)));
                }
            }
        }
    }
}

// ---------------------------------------------------------------------------
// dconv v2: MFMA implicit GEMM over sampled patches.
// Block = 64 px (16 wide x 4 tall), 256 threads / 4 waves. grid (15, 32, B).
// 18 K-slices of 32; per slice: wave wv samples K-group (dg,tap) for all
// 64 px (one 16B gather per corner from channels-last pin), writes bf16x8
// to LDS S[px][40-pitch]; then every wave does 4 MFMAs (its 16 oc x 64 px).
// A-fragments pre-packed in wdp (global, L2-resident).
// ---------------------------------------------------------------------------
__global__ __launch_bounds__(256) void dconv_mfma(
    const ushort_t* __restrict__ pin,
    const float* __restrict__ offs,
    const ushort_t* __restrict__ maskbuf,
    const ushort_t* __restrict__ wdp, const float* __restrict__ bd,
    float* __restrict__ outp)
{
    const int x0 = blockIdx.x << 4, y0 = blockIdx.y << 2, b = blockIdx.z;
    const int tid = threadIdx.x;
    const int wv = tid >> 6, lane = tid & 63;
    const int l15 = lane & 15, hi4 = lane >> 4;          // hi4 = 0..3

    // sampling role: pixel = lane (col=l15, row=hi4), K-group = wv
    const int x = x0 + l15, y = y0 + hi4;
    const size_t pix = (size_t)y * W_ + x;
    const size_t pinb = (size_t)b * HW_;

    __shared__ __align__(16) ushort_t s_S[64 * 40];      // 5120 B

    f32x4 acc[4];
#pragma unroll
    for (int i = 0; i < 4; ++i) acc[i] = (f32x4){0.f, 0.f, 0.f, 0.f};

    for (int s = 0; s < 18; ++s) {
        // ---------------- sampling ----------------
        {
            const int Kb = (s << 5) + (wv << 3);         // multiple of 8
            const int dg = Kb / 72;
            const int rr = Kb - dg * 72;
            const int tap = rr >> 3;
            const int ky = tap / 3 - 1, kx = tap % 3 - 1;

            float dyv = offs[((size_t)b * OFF_CH + dg * 18 + tap) * HW_ + pix];
            float dxv = offs[((size_t)b * OFF_CH + dg * 18 + 9 + tap) * HW_ + pix];
            float m   = bf2f(maskbuf[((size_t)b * MASK_CH + dg * 9 + tap) * HW_ + pix]);

            float py  = (float)(y + ky) + dyv;
            float pxf = (float)(x + kx) + dxv;
            float yf = floorf(py), xf = floorf(pxf);
            float wy = py - yf, wx = pxf - xf;
            int yi = (int)yf, xi = (int)xf;

            const bool y0v = (unsigned)yi < (unsigned)H_;
            const bool y1v = (unsigned)(yi + 1) < (unsigned)H_;
            const bool x0v = (unsigned)xi < (unsigned)W_;
            const bool x1v = (unsigned)(xi + 1) < (unsigned)W_;

            float w00 = (1.f - wy) * (1.f - wx) * m; if (!(y0v && x0v)) w00 = 0.f;
            float w01 = (1.f - wy) * wx        * m; if (!(y0v && x1v)) w01 = 0.f;
            float w10 = wy        * (1.f - wx) * m; if (!(y1v && x0v)) w10 = 0.f;
            float w11 = wy        * wx         * m; if (!(y1v && x1v)) w11 = 0.f;

            int yc0 = min(max(yi, 0), H_ - 1), yc1 = min(max(yi + 1, 0), H_ - 1);
            int xc0 = min(max(xi, 0), W_ - 1), xc1 = min(max(xi + 1, 0), W_ - 1);

            const int cofs = dg << 3;                    // nbr channels of this dg
            int4 q00 = *(const int4*)&pin[(pinb + yc0 * W_ + xc0) * 128 + cofs];
            int4 q01 = *(const int4*)&pin[(pinb + yc0 * W_ + xc1) * 128 + cofs];
            int4 q10 = *(const int4*)&pin[(pinb + yc1 * W_ + xc0) * 128 + cofs];
            int4 q11 = *(const int4*)&pin[(pinb + yc1 * W_ + xc1) * 128 + cofs];

            union { ushort_t u[8]; int4 v; } o;
            const int* a00 = (const int*)&q00; const int* a01 = (const int*)&q01;
            const int* a10 = (const int*)&q10; const int* a11 = (const int*)&q11;
#pragma unroll
            for (int j = 0; j < 4; ++j) {
                float lo = w00 * bf_lo(a00[j]) + w01 * bf_lo(a01[j])
                         + w10 * bf_lo(a10[j]) + w11 * bf_lo(a11[j]);
                float hv = w00 * bf_hi(a00[j]) + w01 * bf_hi(a01[j])
                         + w10 * bf_hi(a10[j]) + w11 * bf_hi(a11[j]);
                o.u[2 * j]     = f2bf(lo);
                o.u[2 * j + 1] = f2bf(hv);
            }
            *(int4*)&s_S[lane * 40 + (wv << 3)] = o.v;
        }
        __syncthreads();

        // ---------------- MFMA ----------------
        bf16x8 a = *(const bf16x8*)&wdp[(((size_t)(s << 2) + wv) * 64 + lane) << 3];
#pragma unroll
        for (int pg = 0; pg < 4; ++pg) {
            bf16x8 bb = *(const bf16x8*)&s_S[((pg << 4) + l15) * 40 + (hi4 << 3)];
            acc[pg] = __builtin_amdgcn_mfma_f32_16x16x32_bf16(a, bb, acc[pg], 0, 0, 0);
        }
        __syncthreads();
    }

    // epilogue: D row = hi4*4 + r -> oc = wv*16 + hi4*4 + r; D col = l15 = px col
    const int ocb = (wv << 4) + (hi4 << 2);
#pragma unroll
    for (int pg = 0; pg < 4; ++pg) {
#pragma unroll
        for (int r = 0; r < 4; ++r) {
            int oc = ocb + r;
            outp[((size_t)b * C_ + oc) * HW_ + (size_t)(y0 + pg) * W_ + x0 + l15] =
                acc[pg][r] + bd[oc];
        }
    }
}

// ---------------------------------------------------------------------------
extern "C" void kernel_launch(void* const* d_in, const int* in_sizes, int n_in,
                              void* d_out, int out_size, void* d_ws, size_t ws_size,
                              hipStream_t stream)
{
    const float* nbr = (const float*)d_in[0];
    const float* ref = (const float*)d_in[1];
    const float* w1  = (const float*)d_in[2];
    const float* b1  = (const float*)d_in[3];
    const float* w2  = (const float*)d_in[4];
    const float* b2  = (const float*)d_in[5];
    const float* wd  = (const float*)d_in[6];
    const float* bd  = (const float*)d_in[7];

    float* out     = (float*)d_out;
    float* off_out = out + ALIGNED_SZ;

    char* ws = (char*)d_ws;
    ushort_t* w1p   = (ushort_t*)(ws + W1P_OFF);
    ushort_t* w2p   = (ushort_t*)(ws + W2P_OFF);
    ushort_t* pin   = (ushort_t*)(ws + PIN_OFF);
    ushort_t* hbufp = (ushort_t*)(ws + HBUF_OFF);
    ushort_t* maskp = (ushort_t*)(ws + MASK_OFF);
    ushort_t* wdp   = (ushort_t*)(ws + WDP_OFF);

    dim3 blk(256, 1, 1);
    pack_weights<<<936, blk, 0, stream>>>(w1, w2, wd, w1p, w2p, wdp);
    pack_input<<<3840, blk, 0, stream>>>(nbr, ref, pin);
    conv1_mfma<<<dim3(5, 128, 2), blk, 0, stream>>>(pin, b1, w1p, hbufp);
    conv2_mfma<<<dim3(5, 128, 8), blk, 0, stream>>>(hbufp, b2, w2p, off_out, maskp);
    dconv_mfma<<<dim3(15, 32, 2), blk, 0, stream>>>(pin, off_out, maskp, wdp, bd, out);
}

// Round 5
// 229.685 us; speedup vs baseline: 8.8334x; 1.1902x over previous
//
#include <hip/hip_runtime.h>
#include <cstdint>
#include <cmath>

#define B_ 2
#define C_ 64
#define H_ 128
#define W_ 240
#define HW_ (H_*W_)
#define OFF_CH 144
#define MASK_CH 72
#define ALIGNED_SZ (B_*C_*HW_)   /* 3932160 floats */

typedef __bf16 bf16x8 __attribute__((ext_vector_type(8)));
typedef float f32x4 __attribute__((ext_vector_type(4)));
typedef short short4v __attribute__((ext_vector_type(4)));
typedef unsigned short ushort_t;

__device__ __forceinline__ ushort_t f2bf(float f) {
    unsigned u = __float_as_uint(f);
    u += 0x7fffu + ((u >> 16) & 1u);          // round-to-nearest-even
    return (ushort_t)(u >> 16);
}
__device__ __forceinline__ float bf2f(ushort_t b) {
    return __uint_as_float((unsigned)b << 16);
}
__device__ __forceinline__ float bf_lo(int q) {
    return __uint_as_float((unsigned)q << 16);
}
__device__ __forceinline__ float bf_hi(int q) {
    return __uint_as_float((unsigned)q & 0xffff0000u);
}

// workspace layout (byte offsets); total 32,919,552 B (< 33.4 MB proven OK)
// pin is now SPLIT: [B][2(half: 0=nbr,1=ref)][HW][64] bf16 — same size.
#define W1P_OFF  0u           /* [9][64][128]  bf16 = 147,456 B  */
#define W2P_OFF  147456u      /* [9][224][64]  bf16 = 258,048 B  */
#define PIN_OFF  405504u      /* [B][2][HW][64] bf16 = 15,728,640 */
#define HBUF_OFF 16134144u    /* [B][H][W][64]  bf16 =  7,864,320 */
#define MASK_OFF 23998464u    /* [B][72][H][W]  bf16 =  8,847,360 */
#define WDP_OFF  32845824u    /* [18][4][64][8] bf16 =     73,728 */

// ---------------------------------------------------------------------------
// Repack weights (unchanged from round 4).
// ---------------------------------------------------------------------------
__global__ __launch_bounds__(256) void pack_weights(
    const float* __restrict__ w1, const float* __restrict__ w2,
    const float* __restrict__ wd,
    ushort_t* __restrict__ w1p, ushort_t* __restrict__ w2p,
    ushort_t* __restrict__ wdp)
{
    int t = blockIdx.x * 256 + threadIdx.x;
    if (t < 73728) {
        int ci = t & 127, r = t >> 7;          // r = tap*64 + oc
        int oc = r & 63, tap = r >> 6;
        w1p[t] = f2bf(w1[((size_t)oc * 128 + ci) * 9 + tap]);
    } else if (t < 73728 + 129024) {
        int f = t - 73728;                     // f = (tap*224 + oc)*64 + ci
        int ci = f & 63, r = f >> 6;
        int oc = r % 224, tap = r / 224;
        float v = (oc < 216) ? w2[((size_t)oc * 64 + ci) * 9 + tap] : 0.f;
        w2p[f] = f2bf(v);
    } else if (t < 73728 + 129024 + 36864) {
        int f = t - 202752;
        int j = f & 7, lane = (f >> 3) & 63, sg = f >> 9;  // sg = s*4+g
        int g = sg & 3, s = sg >> 2;
        int oc = g * 16 + (lane & 15);
        int K = s * 32 + ((lane >> 4) << 3) + j;
        int dg = K / 72, rr = K - dg * 72;
        int tap = rr >> 3, ci = (dg << 3) + (rr & 7);
        wdp[f] = f2bf(wd[((size_t)oc * 64 + ci) * 9 + tap]);
    }
}

// ---------------------------------------------------------------------------
// Repack input into SPLIT layout: pin[((b*2+half)*HW + pix)*64 + c]
// half 0 = nbr channels 0..63, half 1 = ref channels 0..63.
// ---------------------------------------------------------------------------
__global__ __launch_bounds__(256) void pack_input(
    const float* __restrict__ nbr, const float* __restrict__ ref,
    ushort_t* __restrict__ pin)
{
    int f = blockIdx.x * 256 + threadIdx.x;    // < 983040 = B*HW*16
    int civec = f & 15;
    int rem = f >> 4;                          // b*HW + pix
    int b = rem / HW_, pix = rem - b * HW_;
    const int half = civec >> 3;
    const float* src = (half == 0) ? (nbr + (size_t)b * 64 * HW_)
                                   : (ref + (size_t)b * 64 * HW_);
    int cbase = (civec & 7) * 8;
    union { ushort_t u[8]; int4 v; } o;
#pragma unroll
    for (int j = 0; j < 8; ++j)
        o.u[j] = f2bf(src[(size_t)(cbase + j) * HW_ + pix]);
    *(int4*)&pin[(((size_t)b * 2 + half) * HW_ + pix) * 64 + cbase] = o.v;
}

// ---------------------------------------------------------------------------
// conv1 via MFMA implicit GEMM (address math adapted to split pin layout).
// ---------------------------------------------------------------------------
__global__ __launch_bounds__(256) void conv1_mfma(
    const ushort_t* __restrict__ pin, const float* __restrict__ b1,
    const ushort_t* __restrict__ w1p, ushort_t* __restrict__ hbuf)
{
    const int bx = blockIdx.x, y = blockIdx.y, b = blockIdx.z;
    const int x0 = bx * 48;
    const int tid = threadIdx.x;
    const int wv = tid >> 6, lane = tid & 63;
    const int l15 = lane & 15, k8 = (lane >> 4) << 3;

    __shared__ __align__(16) ushort_t s_in[3 * 50 * 40];
    __shared__ __align__(16) ushort_t s_w[9 * 64 * 40];

    f32x4 acc[3];
#pragma unroll
    for (int i = 0; i < 3; ++i) acc[i] = (f32x4){0.f, 0.f, 0.f, 0.f};

    for (int chunk = 0; chunk < 4; ++chunk) {
        const int ci0 = chunk << 5;
        for (int i = tid; i < 600; i += 256) {
            int cvec = i & 3, rc = i >> 2;
            int row = rc / 50, col = rc - row * 50;
            int gy = y + row - 1, gx = x0 + col - 1;
            int ci = ci0 + cvec * 8;
            int half = ci >> 6, cw = ci & 63;
            int4 v = {0, 0, 0, 0};
            if ((unsigned)gy < (unsigned)H_ && (unsigned)gx < (unsigned)W_)
                v = *(const int4*)&pin[(((size_t)b * 2 + half) * HW_ + (size_t)gy * W_ + gx) * 64 + cw];
            *(int4*)&s_in[(row * 50 + col) * 40 + cvec * 8] = v;
        }
        for (int i = tid; i < 2304; i += 256) {
            int cvec = i & 3, to = i >> 2;
            int4 v = *(const int4*)&w1p[(size_t)to * 128 + ci0 + cvec * 8];
            *(int4*)&s_w[to * 40 + cvec * 8] = v;
        }
        __syncthreads();

#pragma unroll
        for (int tap = 0; tap < 9; ++tap) {
            const int ky = tap / 3, kx = tap - ky * 3;
            bf16x8 a = *(const bf16x8*)&s_w[((tap * 64) + (wv << 4) + l15) * 40 + k8];
#pragma unroll
            for (int pt = 0; pt < 3; ++pt) {
                int col = (pt << 4) + l15 + kx;
                bf16x8 bb = *(const bf16x8*)&s_in[(ky * 50 + col) * 40 + k8];
                acc[pt] = __builtin_amdgcn_mfma_f32_16x16x32_bf16(a, bb, acc[pt], 0, 0, 0);
            }
        }
        __syncthreads();
    }

    const int ocb = (wv << 4) + ((lane >> 4) << 2);
    float bias[4];
#pragma unroll
    for (int r = 0; r < 4; ++r) bias[r] = b1[ocb + r];
#pragma unroll
    for (int pt = 0; pt < 3; ++pt) {
        int gx = x0 + (pt << 4) + l15;
        union { ushort_t u[4]; short4v s; } o;
#pragma unroll
        for (int r = 0; r < 4; ++r) {
            float v = acc[pt][r] + bias[r];
            v = (v >= 0.f) ? v : 0.1f * v;
            o.u[r] = f2bf(v);
        }
        *(short4v*)&hbuf[(((size_t)b * H_ + y) * W_ + gx) * 64 + ocb] = o.s;
    }
}

// ---------------------------------------------------------------------------
// conv2 via MFMA implicit GEMM (unchanged, proven).
// ---------------------------------------------------------------------------
__global__ __launch_bounds__(256) void conv2_mfma(
    const ushort_t* __restrict__ hbuf, const float* __restrict__ b2,
    const ushort_t* __restrict__ w2p,
    float* __restrict__ off_out, ushort_t* __restrict__ maskbuf)
{
    const int bx = blockIdx.x, y = blockIdx.y;
    const int b = blockIdx.z >> 2, ocg = blockIdx.z & 3;
    const int x0 = bx * 48;
    const int tid = threadIdx.x;
    const int wv = tid >> 6, lane = tid & 63;
    const int l15 = lane & 15, k8 = (lane >> 4) << 3;

    __shared__ __align__(16) ushort_t s_in[3 * 50 * 40];
    __shared__ __align__(16) ushort_t s_w[9 * 64 * 40];

    f32x4 acc[3];
#pragma unroll
    for (int i = 0; i < 3; ++i) acc[i] = (f32x4){0.f, 0.f, 0.f, 0.f};

    for (int chunk = 0; chunk < 2; ++chunk) {
        const int ci0 = chunk << 5;
        for (int i = tid; i < 600; i += 256) {
            int cvec = i & 3, rc = i >> 2;
            int row = rc / 50, col = rc - row * 50;
            int gy = y + row - 1, gx = x0 + col - 1;
            int4 v = {0, 0, 0, 0};
            if ((unsigned)gy < (unsigned)H_ && (unsigned)gx < (unsigned)W_)
                v = *(const int4*)&hbuf[(((size_t)b * H_ + gy) * W_ + gx) * 64 + ci0 + cvec * 8];
            *(int4*)&s_in[(row * 50 + col) * 40 + cvec * 8] = v;
        }
        for (int i = tid; i < 2304; i += 256) {
            int cvec = i & 3, to = i >> 2;
            int tap = to >> 6, oc_l = to & 63;
            int4 v = *(const int4*)&w2p[((size_t)tap * 224 + (ocg << 6) + oc_l) * 64 + ci0 + cvec * 8];
            *(int4*)&s_w[to * 40 + cvec * 8] = v;
        }
        __syncthreads();

#pragma unroll
        for (int tap = 0; tap < 9; ++tap) {
            const int ky = tap / 3, kx = tap - ky * 3;
            bf16x8 a = *(const bf16x8*)&s_w[((tap * 64) + (wv << 4) + l15) * 40 + k8];
#pragma unroll
            for (int pt = 0; pt < 3; ++pt) {
                int col = (pt << 4) + l15 + kx;
                bf16x8 bb = *(const bf16x8*)&s_in[(ky * 50 + col) * 40 + k8];
                acc[pt] = __builtin_amdgcn_mfma_f32_16x16x32_bf16(a, bb, acc[pt], 0, 0, 0);
            }
        }
        __syncthreads();
    }

    const int ocb = (wv << 4) + ((lane >> 4) << 2);
#pragma unroll
    for (int pt = 0; pt < 3; ++pt) {
        int gx = x0 + (pt << 4) + l15;
#pragma unroll
        for (int r = 0; r < 4; ++r) {
            int co = (ocg << 6) + ocb + r;
            if (co < 216) {
                float v = acc[pt][r] + b2[co];
                if (co < 144) {
                    off_out[((size_t)b * OFF_CH + co) * HW_ + y * W_ + gx] = v;
                } else {
                    maskbuf[((size_t)b * MASK_CH + (co - 144)) * HW_ + y * W_ + gx] =
                        f2bf(1.f / (1.f + expf(-v)));
                }
            }
        }
    }
}

// ---------------------------------------------------------------------------
// dconv v3: MFMA implicit GEMM, 128-px tile (16 wide x 8 tall), 256 threads,
// XCD-chunked grid swizzle (480 blocks, 60/XCD = contiguous 4-row bands).
// Per K-slice of 32: 512 sampling tasks (px 0..127 x Kgroup 0..3), 2/thread;
// gathers hit the contiguous nbr half of split pin (128 B/px records).
// ---------------------------------------------------------------------------
__global__ __launch_bounds__(256) void dconv_mfma(
    const ushort_t* __restrict__ pin,
    const float* __restrict__ offs,
    const ushort_t* __restrict__ maskbuf,
    const ushort_t* __restrict__ wdp, const float* __restrict__ bd,
    float* __restrict__ outp)
{
    // XCD-aware swizzle: 480 blocks, 8 XCDs, 60 contiguous per XCD
    const int bid = blockIdx.x;
    const int nid = (bid & 7) * 60 + (bid >> 3);
    const int b   = nid / 240;
    const int rr_ = nid - b * 240;
    const int byt = rr_ / 15, bxt = rr_ - byt * 15;
    const int x0 = bxt << 4, y0 = byt << 3;

    const int tid = threadIdx.x;
    const int wv = tid >> 6, lane = tid & 63;
    const int l15 = lane & 15, hi4 = lane >> 4;

    const size_t pinb = ((size_t)b * 2) * HW_;           // nbr half base (px records)

    __shared__ __align__(16) ushort_t s_S[128 * 40];     // 10,240 B

    f32x4 acc[8];
#pragma unroll
    for (int i = 0; i < 8; ++i) acc[i] = (f32x4){0.f, 0.f, 0.f, 0.f};

    for (int s = 0; s < 18; ++s) {
        // ---------------- sampling: 2 tasks per thread ----------------
#pragma unroll
        for (int half = 0; half < 2; ++half) {
            const int t = tid + half * 256;              // 0..511
            const int pxl = t & 127;                     // tile-local pixel
            const int g = t >> 7;                        // K-group 0..3
            const int row = pxl >> 4, col = pxl & 15;
            const int x = x0 + col, y = y0 + row;
            const size_t pix = (size_t)y * W_ + x;

            const int Kb = (s << 5) + (g << 3);
            const int dg = Kb / 72;
            const int rr = Kb - dg * 72;
            const int tap = rr >> 3;
            const int ky = tap / 3 - 1, kx = tap % 3 - 1;

            float dyv = offs[((size_t)b * OFF_CH + dg * 18 + tap) * HW_ + pix];
            float dxv = offs[((size_t)b * OFF_CH + dg * 18 + 9 + tap) * HW_ + pix];
            float m   = bf2f(maskbuf[((size_t)b * MASK_CH + dg * 9 + tap) * HW_ + pix]);

            float py  = (float)(y + ky) + dyv;
            float pxf = (float)(x + kx) + dxv;
            float yf = floorf(py), xf = floorf(pxf);
            float wy = py - yf, wx = pxf - xf;
            int yi = (int)yf, xi = (int)xf;

            const bool y0v = (unsigned)yi < (unsigned)H_;
            const bool y1v = (unsigned)(yi + 1) < (unsigned)H_;
            const bool x0v = (unsigned)xi < (unsigned)W_;
            const bool x1v = (unsigned)(xi + 1) < (unsigned)W_;

            float w00 = (1.f - wy) * (1.f - wx) * m; if (!(y0v && x0v)) w00 = 0.f;
            float w01 = (1.f - wy) * wx        * m; if (!(y0v && x1v)) w01 = 0.f;
            float w10 = wy        * (1.f - wx) * m; if (!(y1v && x0v)) w10 = 0.f;
            float w11 = wy        * wx         * m; if (!(y1v && x1v)) w11 = 0.f;

            int yc0 = min(max(yi, 0), H_ - 1), yc1 = min(max(yi + 1, 0), H_ - 1);
            int xc0 = min(max(xi, 0), W_ - 1), xc1 = min(max(xi + 1, 0), W_ - 1);

            const int cofs = dg << 3;
            int4 q00 = *(const int4*)&pin[(pinb + yc0 * W_ + xc0) * 64 + cofs];
            int4 q01 = *(const int4*)&pin[(pinb + yc0 * W_ + xc1) * 64 + cofs];
            int4 q10 = *(const int4*)&pin[(pinb + yc1 * W_ + xc0) * 64 + cofs];
            int4 q11 = *(const int4*)&pin[(pinb + yc1 * W_ + xc1) * 64 + cofs];

            union { ushort_t u[8]; int4 v; } o;
            const int* a00 = (const int*)&q00; const int* a01 = (const int*)&q01;
            const int* a10 = (const int*)&q10; const int* a11 = (const int*)&q11;
#pragma unroll
            for (int j = 0; j < 4; ++j) {
                float lo = w00 * bf_lo(a00[j]) + w01 * bf_lo(a01[j])
                         + w10 * bf_lo(a10[j]) + w11 * bf_lo(a11[j]);
                float hv = w00 * bf_hi(a00[j]) + w01 * bf_hi(a01[j])
                         + w10 * bf_hi(a10[j]) + w11 * bf_hi(a11[j]);
                o.u[2 * j]     = f2bf(lo);
                o.u[2 * j + 1] = f2bf(hv);
            }
            *(int4*)&s_S[pxl * 40 + (g << 3)] = o.v;
        }
        __syncthreads();

        // ---------------- MFMA: 8 px-groups per wave ----------------
        bf16x8 a = *(const bf16x8*)&wdp[(((size_t)(s << 2) + wv) * 64 + lane) << 3];
#pragma unroll
        for (int pg = 0; pg < 8; ++pg) {
            bf16x8 bb = *(const bf16x8*)&s_S[((pg << 4) + l15) * 40 + (hi4 << 3)];
            acc[pg] = __builtin_amdgcn_mfma_f32_16x16x32_bf16(a, bb, acc[pg], 0, 0, 0);
        }
        __syncthreads();
    }

    // epilogue: oc = wv*16 + hi4*4 + r; px row = pg, col = l15
    const int ocb = (wv << 4) + (hi4 << 2);
#pragma unroll
    for (int pg = 0; pg < 8; ++pg) {
#pragma unroll
        for (int r = 0; r < 4; ++r) {
            int oc = ocb + r;
            outp[((size_t)b * C_ + oc) * HW_ + (size_t)(y0 + pg) * W_ + x0 + l15] =
                acc[pg][r] + bd[oc];
        }
    }
}

// ---------------------------------------------------------------------------
extern "C" void kernel_launch(void* const* d_in, const int* in_sizes, int n_in,
                              void* d_out, int out_size, void* d_ws, size_t ws_size,
                              hipStream_t stream)
{
    const float* nbr = (const float*)d_in[0];
    const float* ref = (const float*)d_in[1];
    const float* w1  = (const float*)d_in[2];
    const float* b1  = (const float*)d_in[3];
    const float* w2  = (const float*)d_in[4];
    const float* b2  = (const float*)d_in[5];
    const float* wd  = (const float*)d_in[6];
    const float* bd  = (const float*)d_in[7];

    float* out     = (float*)d_out;
    float* off_out = out + ALIGNED_SZ;

    char* ws = (char*)d_ws;
    ushort_t* w1p   = (ushort_t*)(ws + W1P_OFF);
    ushort_t* w2p   = (ushort_t*)(ws + W2P_OFF);
    ushort_t* pin   = (ushort_t*)(ws + PIN_OFF);
    ushort_t* hbufp = (ushort_t*)(ws + HBUF_OFF);
    ushort_t* maskp = (ushort_t*)(ws + MASK_OFF);
    ushort_t* wdp   = (ushort_t*)(ws + WDP_OFF);

    dim3 blk(256, 1, 1);
    pack_weights<<<936, blk, 0, stream>>>(w1, w2, wd, w1p, w2p, wdp);
    pack_input<<<3840, blk, 0, stream>>>(nbr, ref, pin);
    conv1_mfma<<<dim3(5, 128, 2), blk, 0, stream>>>(pin, b1, w1p, hbufp);
    conv2_mfma<<<dim3(5, 128, 8), blk, 0, stream>>>(hbufp, b2, w2p, off_out, maskp);
    dconv_mfma<<<480, blk, 0, stream>>>(pin, off_out, maskp, wdp, bd, out);
}

// Round 6
// 150.594 us; speedup vs baseline: 13.4726x; 1.5252x over previous
//
#include <hip/hip_runtime.h>
#include <cstdint>
#include <cmath>

#define B_ 2
#define C_ 64
#define H_ 128
#define W_ 240
#define HW_ (H_*W_)
#define OFF_CH 144
#define MASK_CH 72
#define ALIGNED_SZ (B_*C_*HW_)   /* 3932160 floats */

typedef __bf16 bf16x8 __attribute__((ext_vector_type(8)));
typedef float f32x4 __attribute__((ext_vector_type(4)));
typedef short short4v __attribute__((ext_vector_type(4)));
typedef unsigned short ushort_t;

__device__ __forceinline__ ushort_t f2bf(float f) {
    unsigned u = __float_as_uint(f);
    u += 0x7fffu + ((u >> 16) & 1u);          // round-to-nearest-even
    return (ushort_t)(u >> 16);
}
__device__ __forceinline__ float bf2f(ushort_t b) {
    return __uint_as_float((unsigned)b << 16);
}
__device__ __forceinline__ float bf_lo(int q) {
    return __uint_as_float((unsigned)q << 16);
}
__device__ __forceinline__ float bf_hi(int q) {
    return __uint_as_float((unsigned)q & 0xffff0000u);
}

// workspace layout (byte offsets); total 32,956,416 B (< 33.4 MB proven OK)
// Conv weights now stored in EXACT MFMA A-fragment order (read from global):
//   w1pf [chunk4][tap9][wv4][lane64][8]            = 147,456 B
//   w2pf [ocg4][chunk2][tap9][wv4][lane64][8]      = 294,912 B
#define W1P_OFF  0u
#define W2P_OFF  147456u
#define PIN_OFF  442368u      /* [B][2][HW][64] bf16 = 15,728,640 */
#define HBUF_OFF 16171008u    /* [B][H][W][64]  bf16 =  7,864,320 */
#define MASK_OFF 24035328u    /* [B][72][H][W]  bf16 =  8,847,360 */
#define WDP_OFF  32882688u    /* [18][4][64][8] bf16 =     73,728 */

// ---------------------------------------------------------------------------
// Repack all weights into MFMA A-fragment layouts.
//   oc = wv*16 + (lane&15);  ci = chunk*32 + (lane>>4)*8 + j
// ---------------------------------------------------------------------------
__global__ __launch_bounds__(256) void pack_weights(
    const float* __restrict__ w1, const float* __restrict__ w2,
    const float* __restrict__ wd,
    ushort_t* __restrict__ w1pf, ushort_t* __restrict__ w2pf,
    ushort_t* __restrict__ wdp)
{
    int t = blockIdx.x * 256 + threadIdx.x;
    if (t < 73728) {
        // w1pf: r = (chunk*9 + tap)*4 + wv
        int j = t & 7, lane = (t >> 3) & 63, r = t >> 9;
        int wv = r & 3, ct = r >> 2;
        int tap = ct % 9, chunk = ct / 9;
        int oc = wv * 16 + (lane & 15);
        int ci = chunk * 32 + ((lane >> 4) << 3) + j;
        w1pf[t] = f2bf(w1[((size_t)oc * 128 + ci) * 9 + tap]);
    } else if (t < 73728 + 147456) {
        // w2pf: r = ((ocg*2 + chunk)*9 + tap)*4 + wv
        int f = t - 73728;
        int j = f & 7, lane = (f >> 3) & 63, r = f >> 9;
        int wv = r & 3, q = r >> 2;
        int tap = q % 9, oc2 = q / 9;
        int chunk = oc2 & 1, ocg = oc2 >> 1;
        int oc = ocg * 64 + wv * 16 + (lane & 15);
        int ci = chunk * 32 + ((lane >> 4) << 3) + j;
        float v = (oc < 216) ? w2[((size_t)oc * 64 + ci) * 9 + tap] : 0.f;
        w2pf[f] = f2bf(v);
    } else if (t < 73728 + 147456 + 36864) {
        // wdp (unchanged mapping): [s18][g4][lane][8]
        int f = t - 221184;
        int j = f & 7, lane = (f >> 3) & 63, sg = f >> 9;
        int g = sg & 3, s = sg >> 2;
        int oc = g * 16 + (lane & 15);
        int K = s * 32 + ((lane >> 4) << 3) + j;
        int dg = K / 72, rr = K - dg * 72;
        int tap = rr >> 3, ci = (dg << 3) + (rr & 7);
        wdp[f] = f2bf(wd[((size_t)oc * 64 + ci) * 9 + tap]);
    }
}

// ---------------------------------------------------------------------------
// Repack input into SPLIT layout: pin[((b*2+half)*HW + pix)*64 + c]
// ---------------------------------------------------------------------------
__global__ __launch_bounds__(256) void pack_input(
    const float* __restrict__ nbr, const float* __restrict__ ref,
    ushort_t* __restrict__ pin)
{
    int f = blockIdx.x * 256 + threadIdx.x;    // < 983040 = B*HW*16
    int civec = f & 15;
    int rem = f >> 4;                          // b*HW + pix
    int b = rem / HW_, pix = rem - b * HW_;
    const int half = civec >> 3;
    const float* src = (half == 0) ? (nbr + (size_t)b * 64 * HW_)
                                   : (ref + (size_t)b * 64 * HW_);
    int cbase = (civec & 7) * 8;
    union { ushort_t u[8]; int4 v; } o;
#pragma unroll
    for (int j = 0; j < 8; ++j)
        o.u[j] = f2bf(src[(size_t)(cbase + j) * HW_ + pix]);
    *(int4*)&pin[(((size_t)b * 2 + half) * HW_ + pix) * 64 + cbase] = o.v;
}

// ---------------------------------------------------------------------------
// conv1 via MFMA implicit GEMM; weights read per-fragment from global w1pf
// (no s_w LDS). LDS = s_in only (12 KB) -> high occupancy.
// ---------------------------------------------------------------------------
__global__ __launch_bounds__(256) void conv1_mfma(
    const ushort_t* __restrict__ pin, const float* __restrict__ b1,
    const ushort_t* __restrict__ w1pf, ushort_t* __restrict__ hbuf)
{
    const int bx = blockIdx.x, y = blockIdx.y, b = blockIdx.z;
    const int x0 = bx * 48;
    const int tid = threadIdx.x;
    const int wv = tid >> 6, lane = tid & 63;
    const int l15 = lane & 15, k8 = (lane >> 4) << 3;

    __shared__ __align__(16) ushort_t s_in[3 * 50 * 40];

    f32x4 acc[3];
#pragma unroll
    for (int i = 0; i < 3; ++i) acc[i] = (f32x4){0.f, 0.f, 0.f, 0.f};

    for (int chunk = 0; chunk < 4; ++chunk) {
        const int ci0 = chunk << 5;
        for (int i = tid; i < 600; i += 256) {
            int cvec = i & 3, rc = i >> 2;
            int row = rc / 50, col = rc - row * 50;
            int gy = y + row - 1, gx = x0 + col - 1;
            int ci = ci0 + cvec * 8;
            int half = ci >> 6, cw = ci & 63;
            int4 v = {0, 0, 0, 0};
            if ((unsigned)gy < (unsigned)H_ && (unsigned)gx < (unsigned)W_)
                v = *(const int4*)&pin[(((size_t)b * 2 + half) * HW_ + (size_t)gy * W_ + gx) * 64 + cw];
            *(int4*)&s_in[(row * 50 + col) * 40 + cvec * 8] = v;
        }
        // A-fragments straight from global (L2-resident), overlap barrier wait
        bf16x8 af[9];
#pragma unroll
        for (int tap = 0; tap < 9; ++tap)
            af[tap] = *(const bf16x8*)&w1pf[((((size_t)chunk * 9 + tap) * 4 + wv) * 64 + lane) * 8];
        __syncthreads();

#pragma unroll
        for (int tap = 0; tap < 9; ++tap) {
            const int ky = tap / 3, kx = tap - ky * 3;
#pragma unroll
            for (int pt = 0; pt < 3; ++pt) {
                int col = (pt << 4) + l15 + kx;
                bf16x8 bb = *(const bf16x8*)&s_in[(ky * 50 + col) * 40 + k8];
                acc[pt] = __builtin_amdgcn_mfma_f32_16x16x32_bf16(af[tap], bb, acc[pt], 0, 0, 0);
            }
        }
        __syncthreads();
    }

    const int ocb = (wv << 4) + ((lane >> 4) << 2);
    float bias[4];
#pragma unroll
    for (int r = 0; r < 4; ++r) bias[r] = b1[ocb + r];
#pragma unroll
    for (int pt = 0; pt < 3; ++pt) {
        int gx = x0 + (pt << 4) + l15;
        union { ushort_t u[4]; short4v s; } o;
#pragma unroll
        for (int r = 0; r < 4; ++r) {
            float v = acc[pt][r] + bias[r];
            v = (v >= 0.f) ? v : 0.1f * v;
            o.u[r] = f2bf(v);
        }
        *(short4v*)&hbuf[(((size_t)b * H_ + y) * W_ + gx) * 64 + ocb] = o.s;
    }
}

// ---------------------------------------------------------------------------
// conv2 via MFMA implicit GEMM; weights per-fragment from global w2pf.
// ---------------------------------------------------------------------------
__global__ __launch_bounds__(256) void conv2_mfma(
    const ushort_t* __restrict__ hbuf, const float* __restrict__ b2,
    const ushort_t* __restrict__ w2pf,
    float* __restrict__ off_out, ushort_t* __restrict__ maskbuf)
{
    const int bx = blockIdx.x, y = blockIdx.y;
    const int b = blockIdx.z >> 2, ocg = blockIdx.z & 3;
    const int x0 = bx * 48;
    const int tid = threadIdx.x;
    const int wv = tid >> 6, lane = tid & 63;
    const int l15 = lane & 15, k8 = (lane >> 4) << 3;

    __shared__ __align__(16) ushort_t s_in[3 * 50 * 40];

    f32x4 acc[3];
#pragma unroll
    for (int i = 0; i < 3; ++i) acc[i] = (f32x4){0.f, 0.f, 0.f, 0.f};

    for (int chunk = 0; chunk < 2; ++chunk) {
        const int ci0 = chunk << 5;
        for (int i = tid; i < 600; i += 256) {
            int cvec = i & 3, rc = i >> 2;
            int row = rc / 50, col = rc - row * 50;
            int gy = y + row - 1, gx = x0 + col - 1;
            int4 v = {0, 0, 0, 0};
            if ((unsigned)gy < (unsigned)H_ && (unsigned)gx < (unsigned)W_)
                v = *(const int4*)&hbuf[(((size_t)b * H_ + gy) * W_ + gx) * 64 + ci0 + cvec * 8];
            *(int4*)&s_in[(row * 50 + col) * 40 + cvec * 8] = v;
        }
        bf16x8 af[9];
#pragma unroll
        for (int tap = 0; tap < 9; ++tap)
            af[tap] = *(const bf16x8*)&w2pf[(((((size_t)ocg * 2 + chunk) * 9 + tap) * 4 + wv) * 64 + lane) * 8];
        __syncthreads();

#pragma unroll
        for (int tap = 0; tap < 9; ++tap) {
            const int ky = tap / 3, kx = tap - ky * 3;
#pragma unroll
            for (int pt = 0; pt < 3; ++pt) {
                int col = (pt << 4) + l15 + kx;
                bf16x8 bb = *(const bf16x8*)&s_in[(ky * 50 + col) * 40 + k8];
                acc[pt] = __builtin_amdgcn_mfma_f32_16x16x32_bf16(af[tap], bb, acc[pt], 0, 0, 0);
            }
        }
        __syncthreads();
    }

    const int ocb = (wv << 4) + ((lane >> 4) << 2);
#pragma unroll
    for (int pt = 0; pt < 3; ++pt) {
        int gx = x0 + (pt << 4) + l15;
#pragma unroll
        for (int r = 0; r < 4; ++r) {
            int co = (ocg << 6) + ocb + r;
            if (co < 216) {
                float v = acc[pt][r] + b2[co];
                if (co < 144) {
                    off_out[((size_t)b * OFF_CH + co) * HW_ + y * W_ + gx] = v;
                } else {
                    maskbuf[((size_t)b * MASK_CH + (co - 144)) * HW_ + y * W_ + gx] =
                        f2bf(1.f / (1.f + expf(-v)));
                }
            }
        }
    }
}

// ---------------------------------------------------------------------------
// dconv v3 (unchanged from round 5 — proven).
// ---------------------------------------------------------------------------
__global__ __launch_bounds__(256) void dconv_mfma(
    const ushort_t* __restrict__ pin,
    const float* __restrict__ offs,
    const ushort_t* __restrict__ maskbuf,
    const ushort_t* __restrict__ wdp, const float* __restrict__ bd,
    float* __restrict__ outp)
{
    const int bid = blockIdx.x;
    const int nid = (bid & 7) * 60 + (bid >> 3);
    const int b   = nid / 240;
    const int rr_ = nid - b * 240;
    const int byt = rr_ / 15, bxt = rr_ - byt * 15;
    const int x0 = bxt << 4, y0 = byt << 3;

    const int tid = threadIdx.x;
    const int wv = tid >> 6, lane = tid & 63;
    const int l15 = lane & 15, hi4 = lane >> 4;

    const size_t pinb = ((size_t)b * 2) * HW_;

    __shared__ __align__(16) ushort_t s_S[128 * 40];

    f32x4 acc[8];
#pragma unroll
    for (int i = 0; i < 8; ++i) acc[i] = (f32x4){0.f, 0.f, 0.f, 0.f};

    for (int s = 0; s < 18; ++s) {
#pragma unroll
        for (int half = 0; half < 2; ++half) {
            const int t = tid + half * 256;
            const int pxl = t & 127;
            const int g = t >> 7;
            const int row = pxl >> 4, col = pxl & 15;
            const int x = x0 + col, y = y0 + row;
            const size_t pix = (size_t)y * W_ + x;

            const int Kb = (s << 5) + (g << 3);
            const int dg = Kb / 72;
            const int rr = Kb - dg * 72;
            const int tap = rr >> 3;
            const int ky = tap / 3 - 1, kx = tap % 3 - 1;

            float dyv = offs[((size_t)b * OFF_CH + dg * 18 + tap) * HW_ + pix];
            float dxv = offs[((size_t)b * OFF_CH + dg * 18 + 9 + tap) * HW_ + pix];
            float m   = bf2f(maskbuf[((size_t)b * MASK_CH + dg * 9 + tap) * HW_ + pix]);

            float py  = (float)(y + ky) + dyv;
            float pxf = (float)(x + kx) + dxv;
            float yf = floorf(py), xf = floorf(pxf);
            float wy = py - yf, wx = pxf - xf;
            int yi = (int)yf, xi = (int)xf;

            const bool y0v = (unsigned)yi < (unsigned)H_;
            const bool y1v = (unsigned)(yi + 1) < (unsigned)H_;
            const bool x0v = (unsigned)xi < (unsigned)W_;
            const bool x1v = (unsigned)(xi + 1) < (unsigned)W_;

            float w00 = (1.f - wy) * (1.f - wx) * m; if (!(y0v && x0v)) w00 = 0.f;
            float w01 = (1.f - wy) * wx        * m; if (!(y0v && x1v)) w01 = 0.f;
            float w10 = wy        * (1.f - wx) * m; if (!(y1v && x0v)) w10 = 0.f;
            float w11 = wy        * wx         * m; if (!(y1v && x1v)) w11 = 0.f;

            int yc0 = min(max(yi, 0), H_ - 1), yc1 = min(max(yi + 1, 0), H_ - 1);
            int xc0 = min(max(xi, 0), W_ - 1), xc1 = min(max(xi + 1, 0), W_ - 1);

            const int cofs = dg << 3;
            int4 q00 = *(const int4*)&pin[(pinb + yc0 * W_ + xc0) * 64 + cofs];
            int4 q01 = *(const int4*)&pin[(pinb + yc0 * W_ + xc1) * 64 + cofs];
            int4 q10 = *(const int4*)&pin[(pinb + yc1 * W_ + xc0) * 64 + cofs];
            int4 q11 = *(const int4*)&pin[(pinb + yc1 * W_ + xc1) * 64 + cofs];

            union { ushort_t u[8]; int4 v; } o;
            const int* a00 = (const int*)&q00; const int* a01 = (const int*)&q01;
            const int* a10 = (const int*)&q10; const int* a11 = (const int*)&q11;
#pragma unroll
            for (int j = 0; j < 4; ++j) {
                float lo = w00 * bf_lo(a00[j]) + w01 * bf_lo(a01[j])
                         + w10 * bf_lo(a10[j]) + w11 * bf_lo(a11[j]);
                float hv = w00 * bf_hi(a00[j]) + w01 * bf_hi(a01[j])
                         + w10 * bf_hi(a10[j]) + w11 * bf_hi(a11[j]);
                o.u[2 * j]     = f2bf(lo);
                o.u[2 * j + 1] = f2bf(hv);
            }
            *(int4*)&s_S[pxl * 40 + (g << 3)] = o.v;
        }
        __syncthreads();

        bf16x8 a = *(const bf16x8*)&wdp[(((size_t)(s << 2) + wv) * 64 + lane) << 3];
#pragma unroll
        for (int pg = 0; pg < 8; ++pg) {
            bf16x8 bb = *(const bf16x8*)&s_S[((pg << 4) + l15) * 40 + (hi4 << 3)];
            acc[pg] = __builtin_amdgcn_mfma_f32_16x16x32_bf16(a, bb, acc[pg], 0, 0, 0);
        }
        __syncthreads();
    }

    const int ocb = (wv << 4) + (hi4 << 2);
#pragma unroll
    for (int pg = 0; pg < 8; ++pg) {
#pragma unroll
        for (int r = 0; r < 4; ++r) {
            int oc = ocb + r;
            outp[((size_t)b * C_ + oc) * HW_ + (size_t)(y0 + pg) * W_ + x0 + l15] =
                acc[pg][r] + bd[oc];
        }
    }
}

// ---------------------------------------------------------------------------
extern "C" void kernel_launch(void* const* d_in, const int* in_sizes, int n_in,
                              void* d_out, int out_size, void* d_ws, size_t ws_size,
                              hipStream_t stream)
{
    const float* nbr = (const float*)d_in[0];
    const float* ref = (const float*)d_in[1];
    const float* w1  = (const float*)d_in[2];
    const float* b1  = (const float*)d_in[3];
    const float* w2  = (const float*)d_in[4];
    const float* b2  = (const float*)d_in[5];
    const float* wd  = (const float*)d_in[6];
    const float* bd  = (const float*)d_in[7];

    float* out     = (float*)d_out;
    float* off_out = out + ALIGNED_SZ;

    char* ws = (char*)d_ws;
    ushort_t* w1pf  = (ushort_t*)(ws + W1P_OFF);
    ushort_t* w2pf  = (ushort_t*)(ws + W2P_OFF);
    ushort_t* pin   = (ushort_t*)(ws + PIN_OFF);
    ushort_t* hbufp = (ushort_t*)(ws + HBUF_OFF);
    ushort_t* maskp = (ushort_t*)(ws + MASK_OFF);
    ushort_t* wdp   = (ushort_t*)(ws + WDP_OFF);

    dim3 blk(256, 1, 1);
    pack_weights<<<1008, blk, 0, stream>>>(w1, w2, wd, w1pf, w2pf, wdp);
    pack_input<<<3840, blk, 0, stream>>>(nbr, ref, pin);
    conv1_mfma<<<dim3(5, 128, 2), blk, 0, stream>>>(pin, b1, w1pf, hbufp);
    conv2_mfma<<<dim3(5, 128, 8), blk, 0, stream>>>(hbufp, b2, w2pf, off_out, maskp);
    dconv_mfma<<<480, blk, 0, stream>>>(pin, off_out, maskp, wdp, bd, out);
}

// Round 7
// 146.435 us; speedup vs baseline: 13.8552x; 1.0284x over previous
//
#include <hip/hip_runtime.h>
#include <cstdint>
#include <cmath>

#define B_ 2
#define C_ 64
#define H_ 128
#define W_ 240
#define HW_ (H_*W_)
#define OFF_CH 144
#define MASK_CH 72
#define ALIGNED_SZ (B_*C_*HW_)   /* 3932160 floats */

typedef __bf16 bf16x8 __attribute__((ext_vector_type(8)));
typedef float f32x4 __attribute__((ext_vector_type(4)));
typedef short short4v __attribute__((ext_vector_type(4)));
typedef unsigned short ushort_t;

__device__ __forceinline__ ushort_t f2bf(float f) {
    unsigned u = __float_as_uint(f);
    u += 0x7fffu + ((u >> 16) & 1u);          // round-to-nearest-even
    return (ushort_t)(u >> 16);
}
__device__ __forceinline__ float bf2f(ushort_t b) {
    return __uint_as_float((unsigned)b << 16);
}
__device__ __forceinline__ float bf_lo(int q) {
    return __uint_as_float((unsigned)q << 16);
}
__device__ __forceinline__ float bf_hi(int q) {
    return __uint_as_float((unsigned)q & 0xffff0000u);
}

// workspace layout (byte offsets); total 32,956,416 B (< 33.4 MB proven OK)
#define W1P_OFF  0u
#define W2P_OFF  147456u
#define PIN_OFF  442368u      /* [B][2][HW][64] bf16 = 15,728,640 */
#define HBUF_OFF 16171008u    /* [B][H][W][64]  bf16 =  7,864,320 */
#define MASK_OFF 24035328u    /* [B][72][H][W]  bf16 =  8,847,360 */
#define WDP_OFF  32882688u    /* [18][4][64][8] bf16 =     73,728 */

// ---------------------------------------------------------------------------
// Repack all weights into MFMA A-fragment layouts (unchanged from round 6).
// ---------------------------------------------------------------------------
__global__ __launch_bounds__(256) void pack_weights(
    const float* __restrict__ w1, const float* __restrict__ w2,
    const float* __restrict__ wd,
    ushort_t* __restrict__ w1pf, ushort_t* __restrict__ w2pf,
    ushort_t* __restrict__ wdp)
{
    int t = blockIdx.x * 256 + threadIdx.x;
    if (t < 73728) {
        int j = t & 7, lane = (t >> 3) & 63, r = t >> 9;
        int wv = r & 3, ct = r >> 2;
        int tap = ct % 9, chunk = ct / 9;
        int oc = wv * 16 + (lane & 15);
        int ci = chunk * 32 + ((lane >> 4) << 3) + j;
        w1pf[t] = f2bf(w1[((size_t)oc * 128 + ci) * 9 + tap]);
    } else if (t < 73728 + 147456) {
        int f = t - 73728;
        int j = f & 7, lane = (f >> 3) & 63, r = f >> 9;
        int wv = r & 3, q = r >> 2;
        int tap = q % 9, oc2 = q / 9;
        int chunk = oc2 & 1, ocg = oc2 >> 1;
        int oc = ocg * 64 + wv * 16 + (lane & 15);
        int ci = chunk * 32 + ((lane >> 4) << 3) + j;
        float v = (oc < 216) ? w2[((size_t)oc * 64 + ci) * 9 + tap] : 0.f;
        w2pf[f] = f2bf(v);
    } else if (t < 73728 + 147456 + 36864) {
        int f = t - 221184;
        int j = f & 7, lane = (f >> 3) & 63, sg = f >> 9;
        int g = sg & 3, s = sg >> 2;
        int oc = g * 16 + (lane & 15);
        int K = s * 32 + ((lane >> 4) << 3) + j;
        int dg = K / 72, rr = K - dg * 72;
        int tap = rr >> 3, ci = (dg << 3) + (rr & 7);
        wdp[f] = f2bf(wd[((size_t)oc * 64 + ci) * 9 + tap]);
    }
}

// ---------------------------------------------------------------------------
// Repack input into SPLIT layout (unchanged).
// ---------------------------------------------------------------------------
__global__ __launch_bounds__(256) void pack_input(
    const float* __restrict__ nbr, const float* __restrict__ ref,
    ushort_t* __restrict__ pin)
{
    int f = blockIdx.x * 256 + threadIdx.x;    // < 983040 = B*HW*16
    int civec = f & 15;
    int rem = f >> 4;                          // b*HW + pix
    int b = rem / HW_, pix = rem - b * HW_;
    const int half = civec >> 3;
    const float* src = (half == 0) ? (nbr + (size_t)b * 64 * HW_)
                                   : (ref + (size_t)b * 64 * HW_);
    int cbase = (civec & 7) * 8;
    union { ushort_t u[8]; int4 v; } o;
#pragma unroll
    for (int j = 0; j < 8; ++j)
        o.u[j] = f2bf(src[(size_t)(cbase + j) * HW_ + pix]);
    *(int4*)&pin[(((size_t)b * 2 + half) * HW_ + pix) * 64 + cbase] = o.v;
}

// ---------------------------------------------------------------------------
// conv1 via MFMA implicit GEMM (unchanged from round 6, proven).
// ---------------------------------------------------------------------------
__global__ __launch_bounds__(256) void conv1_mfma(
    const ushort_t* __restrict__ pin, const float* __restrict__ b1,
    const ushort_t* __restrict__ w1pf, ushort_t* __restrict__ hbuf)
{
    const int bx = blockIdx.x, y = blockIdx.y, b = blockIdx.z;
    const int x0 = bx * 48;
    const int tid = threadIdx.x;
    const int wv = tid >> 6, lane = tid & 63;
    const int l15 = lane & 15, k8 = (lane >> 4) << 3;

    __shared__ __align__(16) ushort_t s_in[3 * 50 * 40];

    f32x4 acc[3];
#pragma unroll
    for (int i = 0; i < 3; ++i) acc[i] = (f32x4){0.f, 0.f, 0.f, 0.f};

    for (int chunk = 0; chunk < 4; ++chunk) {
        const int ci0 = chunk << 5;
        for (int i = tid; i < 600; i += 256) {
            int cvec = i & 3, rc = i >> 2;
            int row = rc / 50, col = rc - row * 50;
            int gy = y + row - 1, gx = x0 + col - 1;
            int ci = ci0 + cvec * 8;
            int half = ci >> 6, cw = ci & 63;
            int4 v = {0, 0, 0, 0};
            if ((unsigned)gy < (unsigned)H_ && (unsigned)gx < (unsigned)W_)
                v = *(const int4*)&pin[(((size_t)b * 2 + half) * HW_ + (size_t)gy * W_ + gx) * 64 + cw];
            *(int4*)&s_in[(row * 50 + col) * 40 + cvec * 8] = v;
        }
        bf16x8 af[9];
#pragma unroll
        for (int tap = 0; tap < 9; ++tap)
            af[tap] = *(const bf16x8*)&w1pf[((((size_t)chunk * 9 + tap) * 4 + wv) * 64 + lane) * 8];
        __syncthreads();

#pragma unroll
        for (int tap = 0; tap < 9; ++tap) {
            const int ky = tap / 3, kx = tap - ky * 3;
#pragma unroll
            for (int pt = 0; pt < 3; ++pt) {
                int col = (pt << 4) + l15 + kx;
                bf16x8 bb = *(const bf16x8*)&s_in[(ky * 50 + col) * 40 + k8];
                acc[pt] = __builtin_amdgcn_mfma_f32_16x16x32_bf16(af[tap], bb, acc[pt], 0, 0, 0);
            }
        }
        __syncthreads();
    }

    const int ocb = (wv << 4) + ((lane >> 4) << 2);
    float bias[4];
#pragma unroll
    for (int r = 0; r < 4; ++r) bias[r] = b1[ocb + r];
#pragma unroll
    for (int pt = 0; pt < 3; ++pt) {
        int gx = x0 + (pt << 4) + l15;
        union { ushort_t u[4]; short4v s; } o;
#pragma unroll
        for (int r = 0; r < 4; ++r) {
            float v = acc[pt][r] + bias[r];
            v = (v >= 0.f) ? v : 0.1f * v;
            o.u[r] = f2bf(v);
        }
        *(short4v*)&hbuf[(((size_t)b * H_ + y) * W_ + gx) * 64 + ocb] = o.s;
    }
}

// ---------------------------------------------------------------------------
// conv2 via MFMA implicit GEMM (unchanged from round 6, proven).
// ---------------------------------------------------------------------------
__global__ __launch_bounds__(256) void conv2_mfma(
    const ushort_t* __restrict__ hbuf, const float* __restrict__ b2,
    const ushort_t* __restrict__ w2pf,
    float* __restrict__ off_out, ushort_t* __restrict__ maskbuf)
{
    const int bx = blockIdx.x, y = blockIdx.y;
    const int b = blockIdx.z >> 2, ocg = blockIdx.z & 3;
    const int x0 = bx * 48;
    const int tid = threadIdx.x;
    const int wv = tid >> 6, lane = tid & 63;
    const int l15 = lane & 15, k8 = (lane >> 4) << 3;

    __shared__ __align__(16) ushort_t s_in[3 * 50 * 40];

    f32x4 acc[3];
#pragma unroll
    for (int i = 0; i < 3; ++i) acc[i] = (f32x4){0.f, 0.f, 0.f, 0.f};

    for (int chunk = 0; chunk < 2; ++chunk) {
        const int ci0 = chunk << 5;
        for (int i = tid; i < 600; i += 256) {
            int cvec = i & 3, rc = i >> 2;
            int row = rc / 50, col = rc - row * 50;
            int gy = y + row - 1, gx = x0 + col - 1;
            int4 v = {0, 0, 0, 0};
            if ((unsigned)gy < (unsigned)H_ && (unsigned)gx < (unsigned)W_)
                v = *(const int4*)&hbuf[(((size_t)b * H_ + gy) * W_ + gx) * 64 + ci0 + cvec * 8];
            *(int4*)&s_in[(row * 50 + col) * 40 + cvec * 8] = v;
        }
        bf16x8 af[9];
#pragma unroll
        for (int tap = 0; tap < 9; ++tap)
            af[tap] = *(const bf16x8*)&w2pf[(((((size_t)ocg * 2 + chunk) * 9 + tap) * 4 + wv) * 64 + lane) * 8];
        __syncthreads();

#pragma unroll
        for (int tap = 0; tap < 9; ++tap) {
            const int ky = tap / 3, kx = tap - ky * 3;
#pragma unroll
            for (int pt = 0; pt < 3; ++pt) {
                int col = (pt << 4) + l15 + kx;
                bf16x8 bb = *(const bf16x8*)&s_in[(ky * 50 + col) * 40 + k8];
                acc[pt] = __builtin_amdgcn_mfma_f32_16x16x32_bf16(af[tap], bb, acc[pt], 0, 0, 0);
            }
        }
        __syncthreads();
    }

    const int ocb = (wv << 4) + ((lane >> 4) << 2);
#pragma unroll
    for (int pt = 0; pt < 3; ++pt) {
        int gx = x0 + (pt << 4) + l15;
#pragma unroll
        for (int r = 0; r < 4; ++r) {
            int co = (ocg << 6) + ocb + r;
            if (co < 216) {
                float v = acc[pt][r] + b2[co];
                if (co < 144) {
                    off_out[((size_t)b * OFF_CH + co) * HW_ + y * W_ + gx] = v;
                } else {
                    maskbuf[((size_t)b * MASK_CH + (co - 144)) * HW_ + y * W_ + gx] =
                        f2bf(1.f / (1.f + expf(-v)));
                }
            }
        }
    }
}

// ---------------------------------------------------------------------------
// dconv v4: 16x4 tile (64 px), 960 blocks (3.75 blocks/CU), software-
// pipelined: double-buffered s_S, ONE barrier per slice, gathers for s+1
// issued before the barrier of s (in flight across barrier + MFMA).
// Sampling role: pixel = lane, K-group = wv (one task/thread).
// ---------------------------------------------------------------------------
__global__ __launch_bounds__(256) void dconv_mfma(
    const ushort_t* __restrict__ pin,
    const float* __restrict__ offs,
    const ushort_t* __restrict__ maskbuf,
    const ushort_t* __restrict__ wdp, const float* __restrict__ bd,
    float* __restrict__ outp)
{
    // XCD-aware swizzle: 960 blocks, 120 contiguous per XCD
    const int bid = blockIdx.x;
    const int nid = (bid & 7) * 120 + (bid >> 3);
    const int b   = nid / 480;
    const int rr_ = nid - b * 480;
    const int byt = rr_ / 15, bxt = rr_ - byt * 15;   // byt 0..31
    const int x0 = bxt << 4, y0 = byt << 2;

    const int tid = threadIdx.x;
    const int wv = tid >> 6, lane = tid & 63;
    const int l15 = lane & 15, hi4 = lane >> 4;       // hi4 0..3

    const int x = x0 + l15, y = y0 + hi4;
    const size_t pix = (size_t)y * W_ + x;
    const size_t pinb = (size_t)(b * 2) * HW_;        // nbr half base
    const size_t offb = (size_t)b * OFF_CH * HW_ + pix;
    const size_t mskb = (size_t)b * MASK_CH * HW_ + pix;

    __shared__ __align__(16) ushort_t s_S[2][64 * 40];  // 2 x 5120 B

    f32x4 acc[4];
#pragma unroll
    for (int i = 0; i < 4; ++i) acc[i] = (f32x4){0.f, 0.f, 0.f, 0.f};

    // pipeline carry: bilinear weights + 4 gathered quads for CURRENT slice
    float cw0, cw1, cw2, cw3;
    int4 q0, q1, q2, q3;

    // helper lambda: from (dg,tap,dy,dx,m) compute weights + issue gathers
    auto sample_issue = [&](int dg, int tap, float dyv, float dxv, float m,
                            float& w00, float& w01, float& w10, float& w11,
                            int4& r00, int4& r01, int4& r10, int4& r11) {
        const int ky = tap / 3 - 1, kx = tap % 3 - 1;
        float py  = (float)(y + ky) + dyv;
        float pxf = (float)(x + kx) + dxv;
        float yf = floorf(py), xf = floorf(pxf);
        float wy = py - yf, wx = pxf - xf;
        int yi = (int)yf, xi = (int)xf;
        const bool y0v = (unsigned)yi < (unsigned)H_;
        const bool y1v = (unsigned)(yi + 1) < (unsigned)H_;
        const bool x0v = (unsigned)xi < (unsigned)W_;
        const bool x1v = (unsigned)(xi + 1) < (unsigned)W_;
        w00 = (1.f - wy) * (1.f - wx) * m; if (!(y0v && x0v)) w00 = 0.f;
        w01 = (1.f - wy) * wx        * m; if (!(y0v && x1v)) w01 = 0.f;
        w10 = wy        * (1.f - wx) * m; if (!(y1v && x0v)) w10 = 0.f;
        w11 = wy        * wx         * m; if (!(y1v && x1v)) w11 = 0.f;
        int yc0 = min(max(yi, 0), H_ - 1), yc1 = min(max(yi + 1, 0), H_ - 1);
        int xc0 = min(max(xi, 0), W_ - 1), xc1 = min(max(xi + 1, 0), W_ - 1);
        const int cofs = dg << 3;
        r00 = *(const int4*)&pin[(pinb + yc0 * W_ + xc0) * 64 + cofs];
        r01 = *(const int4*)&pin[(pinb + yc0 * W_ + xc1) * 64 + cofs];
        r10 = *(const int4*)&pin[(pinb + yc1 * W_ + xc0) * 64 + cofs];
        r11 = *(const int4*)&pin[(pinb + yc1 * W_ + xc1) * 64 + cofs];
    };

    // prologue: slice 0
    {
        const int Kb = (wv << 3);
        const int dg = Kb / 72, rr = Kb - dg * 72, tap = rr >> 3;
        float dyv = offs[offb + (size_t)(dg * 18 + tap) * HW_];
        float dxv = offs[offb + (size_t)(dg * 18 + 9 + tap) * HW_];
        float m   = bf2f(maskbuf[mskb + (size_t)(dg * 9 + tap) * HW_]);
        sample_issue(dg, tap, dyv, dxv, m, cw0, cw1, cw2, cw3, q0, q1, q2, q3);
    }

    int c = 0;
#pragma unroll
    for (int s = 0; s < 18; ++s) {
        // ---- issue next slice's offset/mask loads (independent) ----
        float dyn = 0.f, dxn = 0.f, mn = 0.f;
        int dgN = 0, tapN = 0;
        if (s < 17) {
            const int Kb = ((s + 1) << 5) + (wv << 3);
            dgN = Kb / 72;
            const int rr = Kb - dgN * 72;
            tapN = rr >> 3;
            dyn = offs[offb + (size_t)(dgN * 18 + tapN) * HW_];
            dxn = offs[offb + (size_t)(dgN * 18 + 9 + tapN) * HW_];
            mn  = bf2f(maskbuf[mskb + (size_t)(dgN * 9 + tapN) * HW_]);
        }
        // A-fragment for this slice (L2-resident, issued early)
        bf16x8 afrag = *(const bf16x8*)&wdp[(((size_t)(s << 2) + wv) * 64 + lane) << 3];

        // ---- blend current slice (q* in flight since previous iter) ----
        {
            union { ushort_t u[8]; int4 v; } o;
            const int* a00 = (const int*)&q0; const int* a01 = (const int*)&q1;
            const int* a10 = (const int*)&q2; const int* a11 = (const int*)&q3;
#pragma unroll
            for (int j = 0; j < 4; ++j) {
                float lo = cw0 * bf_lo(a00[j]) + cw1 * bf_lo(a01[j])
                         + cw2 * bf_lo(a10[j]) + cw3 * bf_lo(a11[j]);
                float hv = cw0 * bf_hi(a00[j]) + cw1 * bf_hi(a01[j])
                         + cw2 * bf_hi(a10[j]) + cw3 * bf_hi(a11[j]);
                o.u[2 * j]     = f2bf(lo);
                o.u[2 * j + 1] = f2bf(hv);
            }
            *(int4*)&s_S[c][lane * 40 + (wv << 3)] = o.v;
        }

        // ---- compute + issue gathers for next slice (fly across barrier) ----
        float nw0, nw1, nw2, nw3;
        int4 n0, n1, n2, n3;
        if (s < 17)
            sample_issue(dgN, tapN, dyn, dxn, mn, nw0, nw1, nw2, nw3, n0, n1, n2, n3);

        __syncthreads();

        // ---- MFMA from buffer c ----
#pragma unroll
        for (int pg = 0; pg < 4; ++pg) {
            bf16x8 bb = *(const bf16x8*)&s_S[c][((pg << 4) + l15) * 40 + (hi4 << 3)];
            acc[pg] = __builtin_amdgcn_mfma_f32_16x16x32_bf16(afrag, bb, acc[pg], 0, 0, 0);
        }

        c ^= 1;
        if (s < 17) {
            cw0 = nw0; cw1 = nw1; cw2 = nw2; cw3 = nw3;
            q0 = n0; q1 = n1; q2 = n2; q3 = n3;
        }
    }

    // epilogue: oc = wv*16 + hi4*4 + r; px row = pg, col = l15
    const int ocb = (wv << 4) + (hi4 << 2);
#pragma unroll
    for (int pg = 0; pg < 4; ++pg) {
#pragma unroll
        for (int r = 0; r < 4; ++r) {
            int oc = ocb + r;
            outp[((size_t)b * C_ + oc) * HW_ + (size_t)(y0 + pg) * W_ + x0 + l15] =
                acc[pg][r] + bd[oc];
        }
    }
}

// ---------------------------------------------------------------------------
extern "C" void kernel_launch(void* const* d_in, const int* in_sizes, int n_in,
                              void* d_out, int out_size, void* d_ws, size_t ws_size,
                              hipStream_t stream)
{
    const float* nbr = (const float*)d_in[0];
    const float* ref = (const float*)d_in[1];
    const float* w1  = (const float*)d_in[2];
    const float* b1  = (const float*)d_in[3];
    const float* w2  = (const float*)d_in[4];
    const float* b2  = (const float*)d_in[5];
    const float* wd  = (const float*)d_in[6];
    const float* bd  = (const float*)d_in[7];

    float* out     = (float*)d_out;
    float* off_out = out + ALIGNED_SZ;

    char* ws = (char*)d_ws;
    ushort_t* w1pf  = (ushort_t*)(ws + W1P_OFF);
    ushort_t* w2pf  = (ushort_t*)(ws + W2P_OFF);
    ushort_t* pin   = (ushort_t*)(ws + PIN_OFF);
    ushort_t* hbufp = (ushort_t*)(ws + HBUF_OFF);
    ushort_t* maskp = (ushort_t*)(ws + MASK_OFF);
    ushort_t* wdp   = (ushort_t*)(ws + WDP_OFF);

    dim3 blk(256, 1, 1);
    pack_weights<<<1008, blk, 0, stream>>>(w1, w2, wd, w1pf, w2pf, wdp);
    pack_input<<<3840, blk, 0, stream>>>(nbr, ref, pin);
    conv1_mfma<<<dim3(5, 128, 2), blk, 0, stream>>>(pin, b1, w1pf, hbufp);
    conv2_mfma<<<dim3(5, 128, 8), blk, 0, stream>>>(hbufp, b2, w2pf, off_out, maskp);
    dconv_mfma<<<960, blk, 0, stream>>>(pin, off_out, maskp, wdp, bd, out);
}